// Round 7
// baseline (1333.471 us; speedup 1.0000x reference)
//
#include <hip/hip_runtime.h>
#include <hip/hip_bf16.h>

#define B_   4
#define LD_  1024
#define LE_  1024
#define D_   256
#define H_   8
#define DK_  32
#define DFF_ 1024
#define NL_  6
#define NTOK (B_ * LD_)   // 4096 decoder tokens; encoder also 4*1024 = 4096
#define M1E  1048576      // NTOK * D_ elements
#define WTOT 6291456      // total weight elements across 6 layers (frag layout)

typedef __hip_bfloat16 bf16;
typedef __bf16 bf16_t;
typedef bf16_t bf16x8 __attribute__((ext_vector_type(8)));
typedef bf16_t bf16x4 __attribute__((ext_vector_type(4)));
typedef float  f32x4  __attribute__((ext_vector_type(4)));

__device__ __forceinline__ float bits2f(unsigned short u) {
    union { unsigned int i; float f; } w; w.i = ((unsigned int)u) << 16; return w.f;
}
// dtype-flexible scalar load from tensor base + element index
__device__ __forceinline__ float ldx(const void* p, size_t i, int f32) {
    if (f32) return ((const float*)p)[i];
    return bits2f(((const unsigned short*)p)[i]);
}

// ---------------------------------------------------------------------------
// Detect input dtype (bf16 vs fp32). flag: 1=fp32, 0=bf16.
__global__ __launch_bounds__(256) void detect_kernel(
    const void* __restrict__ enc, int* __restrict__ flag)
{
    __shared__ int bad;
    if (threadIdx.x == 0) bad = 0;
    __syncthreads();
    const unsigned short* u = (const unsigned short*)enc;
    int b = 0;
    for (int i = threadIdx.x; i < 4096; i += 256) {
        unsigned short e = (u[i] >> 7) & 0xFF;
        if (e >= 142) b = 1;
    }
    if (b) atomicOr(&bad, 1);
    __syncthreads();
    if (threadIdx.x == 0) *flag = bad;
}

// ---------------------------------------------------------------------------
// Convert ALL weights to B-fragment-ready bf16 layout, once per launch.
// Tensor order per layer (frag-element offsets within layer's 1048576):
//   t0..t7 = sa_Wq,sa_Wk,sa_Wv,sa_Wo,ca_Wq,ca_Wk,ca_Wv,ca_Wo @ t*65536 (256x256)
//   W1 @ 524288 (256x1024), W2 @ 786432 (1024x256)
// Within a tensor [K][N]: element j of frag-group (kb,nb,lane) =
//   W[kb*32 + 8*(lane>>4) + j][nb*16 + (lane&15)]
//   stored at group*8 + j, group = (kb*(N/16) + nb)*64 + lane.
// hi at [idx]; lo at [WTOT + idx] (written only in fp32 mode).
__global__ __launch_bounds__(256) void prep_w_kernel(
    const void* sWq, const void* sWk, const void* sWv, const void* sWo,
    const void* cWq, const void* cWk, const void* cWv, const void* cWo,
    const void* fW1, const void* fW2,
    bf16_t* __restrict__ Wf, const int* __restrict__ flag)
{
    const int f32 = *flag;
    const int g = blockIdx.x * 256 + threadIdx.x;   // 0..786431 frag-groups
    const int li = g >> 17;
    int r = g & 131071;
    const void* src;
    size_t so;
    int N;
    if (r < 65536) {
        int t = r >> 13; r &= 8191;
        N = 256; so = (size_t)li * 65536;
        if      (t == 0) src = sWq; else if (t == 1) src = sWk;
        else if (t == 2) src = sWv; else if (t == 3) src = sWo;
        else if (t == 4) src = cWq; else if (t == 5) src = cWk;
        else if (t == 6) src = cWv; else             src = cWo;
    } else if (r < 98304) {
        r -= 65536; N = 1024; so = (size_t)li * 262144; src = fW1;
    } else {
        r -= 98304; N = 256;  so = (size_t)li * 262144; src = fW2;
    }
    const int lane = r & 63;
    const int q2 = r >> 6;
    int nb, kb;
    if (N == 256) { nb = q2 & 15; kb = q2 >> 4; }
    else          { nb = q2 & 63; kb = q2 >> 6; }
    const int k = kb * 32 + 8 * (lane >> 4);
    const int n = nb * 16 + (lane & 15);
    const size_t out = (size_t)g * 8;
#pragma unroll
    for (int j = 0; j < 8; ++j) {
        float v = ldx(src, so + (size_t)(k + j) * N + n, f32);
        bf16_t hv = (bf16_t)v;
        Wf[out + j] = hv;
        if (f32) Wf[WTOT + out + j] = (bf16_t)(v - (float)hv);
    }
}

// ---------------------------------------------------------------------------
// build PE table [1024][256] once
__global__ __launch_bounds__(256) void pe_build_kernel(float* __restrict__ pe)
{
    int i = blockIdx.x * 256 + threadIdx.x;     // over LD_*D_ = 262144
    int d = i & (D_ - 1);
    int pos = i >> 8;
    int j = d & 127;
    float inv = powf(10000.0f, -2.0f * (float)j / (float)D_);
    float s = (float)pos * inv;
    pe[i] = (d < 128) ? sinf(s) : cosf(s);
}

// x = embed + PE; also emit pre-split hi/lo bf16 (layer-0 proj A operand)
__global__ __launch_bounds__(256) void embed_kernel(
    const void* __restrict__ dec, const void* __restrict__ Wt,
    const void* __restrict__ bt, float* __restrict__ x,
    bf16_t* __restrict__ xhi, bf16_t* __restrict__ xlo,
    const float* __restrict__ pe, const int* __restrict__ flag)
{
    int f32 = *flag;
    int i = blockIdx.x * 256 + threadIdx.x;     // over NTOK * D_
    int d = i & (D_ - 1);
    int t = i >> 8;
    float a0 = ldx(dec, t * 3 + 0, f32);
    float a1 = ldx(dec, t * 3 + 1, f32);
    float a2 = ldx(dec, t * 3 + 2, f32);
    float v = ldx(bt, d, f32) + a0 * ldx(Wt, 0 * D_ + d, f32)
            + a1 * ldx(Wt, 1 * D_ + d, f32) + a2 * ldx(Wt, 2 * D_ + d, f32)
            + pe[i & (LD_ * D_ - 1)];
    x[i] = v;
    bf16_t hv = (bf16_t)v;
    xhi[i] = hv;
    xlo[i] = (bf16_t)(v - (float)hv);
}

// enc -> pre-split hi/lo bf16 (cross-attn K/V proj A operand)
__global__ __launch_bounds__(256) void enc_split_kernel(
    const void* __restrict__ in, bf16_t* __restrict__ ehi, bf16_t* __restrict__ elo,
    const int* __restrict__ flag)
{
    int f32 = *flag;
    int i = blockIdx.x * 256 + threadIdx.x;
    float v = ldx(in, i, f32);
    bf16_t hv = (bf16_t)v;
    ehi[i] = hv;
    elo[i] = (bf16_t)(v - (float)hv);
}

// ---------------------------------------------------------------------------
// Fragment GEMM: C = A @ W + bias. A = pre-split hi/lo bf16 [M][K]; W = Wf
// frags (L2-hot, shared across blocks). ZERO LDS, zero barriers -> fully
// latency-pipelined. BM=32, BN=64, 256 thr = 4 waves (2x2), 4-6 MFMA/K-step.
// mode 1: attention-prep epilogue (z0=Q,z1=K,z2=V fragment layouts, see R5)
// mode 2: C = relu(..) split to hi/lo bf16 [M][N] (FF1 -> h)
// aexact: A-lo identically zero for z>0 in bf16 mode (enc input) -> skip.
__global__ __launch_bounds__(256) void gemmf_kernel(
    const bf16_t* __restrict__ Ah0, const bf16_t* __restrict__ Al0,
    const bf16_t* __restrict__ Ah1, const bf16_t* __restrict__ Al1,
    const bf16_t* __restrict__ Ah2, const bf16_t* __restrict__ Al2,
    const bf16_t* __restrict__ Wf, size_t wfBase, size_t wzStr,
    const void* __restrict__ b0, const void* __restrict__ b1,
    const void* __restrict__ b2, size_t bOff,
    bf16_t* __restrict__ C0, bf16_t* __restrict__ C1,
    bf16_t* __restrict__ C2, bf16_t* __restrict__ Cl,
    int M, int N, int K, int mode, int aexact, const int* __restrict__ flag)
{
    const int f32 = *flag;
    const int z = blockIdx.z;
    const bf16_t* Ah = (z == 0) ? Ah0 : (z == 1) ? Ah1 : Ah2;
    const bf16_t* Al = (z == 0) ? Al0 : (z == 1) ? Al1 : Al2;
    const void* bias = (z == 0) ? b0 : (z == 1) ? b1 : b2;
    bf16_t* Cb = (z == 0) ? C0 : (z == 1) ? C1 : C2;
    const int ax = (!f32 && aexact && z > 0);

    const int tid = threadIdx.x;
    const int m0 = blockIdx.y * 32, n0 = blockIdx.x * 64;
    const int w = tid >> 6, l = tid & 63, l15 = l & 15, lg = l >> 4;
    const int wr = w >> 1, wc = w & 1;

    const bf16_t* wfp = Wf + wfBase + (size_t)z * wzStr;
    const bf16_t* wlp = wfp + WTOT;
    const int nbT = N >> 4;
    const int nb0 = (n0 >> 4) + 2 * wc;

    const bf16_t* ap  = Ah + (size_t)(m0 + 16 * wr + l15) * K + 8 * lg;
    const bf16_t* alp = Al + (size_t)(m0 + 16 * wr + l15) * K + 8 * lg;

    f32x4 acc0 = {0.f, 0.f, 0.f, 0.f};
    f32x4 acc1 = {0.f, 0.f, 0.f, 0.f};
    const int K32 = K >> 5;

#pragma unroll 2
    for (int kb = 0; kb < K32; ++kb) {
        bf16x8 ah  = *(const bf16x8*)(ap + kb * 32);
        bf16x8 bh0 = *(const bf16x8*)(wfp + ((size_t)(kb * nbT + nb0) * 64 + l) * 8);
        bf16x8 bh1 = *(const bf16x8*)(wfp + ((size_t)(kb * nbT + nb0 + 1) * 64 + l) * 8);
        acc0 = __builtin_amdgcn_mfma_f32_16x16x32_bf16(ah, bh0, acc0, 0, 0, 0);
        acc1 = __builtin_amdgcn_mfma_f32_16x16x32_bf16(ah, bh1, acc1, 0, 0, 0);
        if (!ax) {
            bf16x8 al8 = *(const bf16x8*)(alp + kb * 32);
            acc0 = __builtin_amdgcn_mfma_f32_16x16x32_bf16(al8, bh0, acc0, 0, 0, 0);
            acc1 = __builtin_amdgcn_mfma_f32_16x16x32_bf16(al8, bh1, acc1, 0, 0, 0);
        }
        if (f32) {
            bf16x8 bl0 = *(const bf16x8*)(wlp + ((size_t)(kb * nbT + nb0) * 64 + l) * 8);
            bf16x8 bl1 = *(const bf16x8*)(wlp + ((size_t)(kb * nbT + nb0 + 1) * 64 + l) * 8);
            acc0 = __builtin_amdgcn_mfma_f32_16x16x32_bf16(ah, bl0, acc0, 0, 0, 0);
            acc1 = __builtin_amdgcn_mfma_f32_16x16x32_bf16(ah, bl1, acc1, 0, 0, 0);
        }
    }

    // epilogue: C/D layout col=l15, row=4*lg+r
    const int cm = m0 + 16 * wr + 4 * lg;
    const int cn = n0 + 32 * wc + l15;
    const float b0v = ldx(bias, bOff + cn, f32);
    const float b1v = ldx(bias, bOff + cn + 16, f32);
    if (mode == 2) {
#pragma unroll
        for (int r = 0; r < 4; ++r) {
#pragma unroll
            for (int cc = 0; cc < 2; ++cc) {
                float v = (cc == 0 ? acc0[r] : acc1[r]) + (cc == 0 ? b0v : b1v);
                v = fmaxf(v, 0.0f);
                size_t idx = (size_t)(cm + r) * N + cn + 16 * cc;
                bf16_t hv = (bf16_t)v;
                C0[idx] = hv;
                Cl[idx] = (bf16_t)(v - (float)hv);
            }
        }
    } else {
        const float qs = (z == 0) ? 0.17677669529663687f : 1.0f;   // 1/sqrt(32)
#pragma unroll
        for (int r = 0; r < 4; ++r) {
            const int token = cm + r;
#pragma unroll
            for (int cc = 0; cc < 2; ++cc) {
                const int d = cn + 16 * cc;
                const float v = ((cc == 0 ? acc0[r] : acc1[r]) + (cc == 0 ? b0v : b1v)) * qs;
                if (z < 2) {
                    int bb = token >> 10, qw = (token >> 4) & 63, lt = token & 15;
                    int hh = d >> 5, lg2 = (d >> 3) & 3, jj = d & 7;
                    size_t base = ((size_t)((bb * 8 + hh) * 64 + qw)) * 1024
                                + (size_t)(lg2 * 16 + lt) * 8 + jj;
                    bf16_t hv = (bf16_t)v;
                    Cb[base]       = hv;
                    Cb[base + 512] = (bf16_t)(v - (float)hv);
                } else {
                    int bb = token >> 10, ktt = (token >> 6) & 15, c2 = (token >> 5) & 1;
                    int w32 = token & 31;
                    int lg2 = (w32 >> 2) & 3, jj = (w32 >> 4) * 4 + (w32 & 3);
                    int hh = d >> 5, dvh = (d >> 4) & 1, lt = d & 15;
                    size_t base = ((size_t)((bb * 8 + hh) * 16 + ktt)) * 2048
                                + c2 * 1024 + dvh * 512 + (size_t)(lg2 * 16 + lt) * 8 + jj;
                    Cb[base] = (bf16_t)v;
                }
            }
        }
    }
}

// ---------------------------------------------------------------------------
// Fragment GEMM + residual + LayerNorm: x = LN(A@W + bias + x)*g + b [+pe];
// also emits x hi/lo bf16 for the next GEMM. A pre-split hi/lo; W from Wf.
// BM=16, N=256, 1024 thr = 16 waves (wave w owns cols 16w..16w+15).
// No K-loop LDS/barriers; only the tiny LN cross-wave reduce.
__global__ __launch_bounds__(1024) void gemmln_kernel(
    const bf16_t* __restrict__ Ah, const bf16_t* __restrict__ Al,
    const bf16_t* __restrict__ Wf, size_t wfBase,
    const void* __restrict__ bias, float* __restrict__ x,
    bf16_t* __restrict__ xhi, bf16_t* __restrict__ xlo,
    const void* __restrict__ g, const void* __restrict__ bt,
    size_t bOff, int K,
    const float* __restrict__ pe, int addpe, const int* __restrict__ flag)
{
    const int f32 = *flag;
    __shared__ float red1[16][16];
    __shared__ float red2[16][16];
    __shared__ float mrow[16], irow[16];

    const int tid = threadIdx.x;
    const int m0 = blockIdx.x * 16;
    const int w = tid >> 6, l = tid & 63, l15 = l & 15, lg = l >> 4;

    const bf16_t* ap  = Ah + (size_t)(m0 + l15) * K + 8 * lg;
    const bf16_t* alp = Al + (size_t)(m0 + l15) * K + 8 * lg;
    const bf16_t* wfp = Wf + wfBase;
    const bf16_t* wlp = wfp + WTOT;

    f32x4 acc = {0.f, 0.f, 0.f, 0.f};
    const int K32 = K >> 5;

#pragma unroll 2
    for (int kb = 0; kb < K32; ++kb) {
        bf16x8 ah = *(const bf16x8*)(ap + kb * 32);
        bf16x8 bh = *(const bf16x8*)(wfp + ((size_t)(kb * 16 + w) * 64 + l) * 8);
        acc = __builtin_amdgcn_mfma_f32_16x16x32_bf16(ah, bh, acc, 0, 0, 0);
        {
            bf16x8 al8 = *(const bf16x8*)(alp + kb * 32);
            acc = __builtin_amdgcn_mfma_f32_16x16x32_bf16(al8, bh, acc, 0, 0, 0);
        }
        if (f32) {
            bf16x8 bl = *(const bf16x8*)(wlp + ((size_t)(kb * 16 + w) * 64 + l) * 8);
            acc = __builtin_amdgcn_mfma_f32_16x16x32_bf16(ah, bl, acc, 0, 0, 0);
        }
    }

    // ---- v = acc + bias + residual; LN stats (rows 4*lg+r, col c) ----
    const int c = 16 * w + l15;
    const float bv = ldx(bias, bOff + c, f32);
    f32x4 v;
    float s1[4], s2[4];
#pragma unroll
    for (int r = 0; r < 4; ++r) {
        int tok = m0 + 4 * lg + r;
        v[r] = acc[r] + bv + x[(size_t)tok * 256 + c];
        s1[r] = v[r];
        s2[r] = v[r] * v[r];
    }
#pragma unroll
    for (int r = 0; r < 4; ++r) {
        s1[r] += __shfl_xor(s1[r], 1);  s2[r] += __shfl_xor(s2[r], 1);
        s1[r] += __shfl_xor(s1[r], 2);  s2[r] += __shfl_xor(s2[r], 2);
        s1[r] += __shfl_xor(s1[r], 4);  s2[r] += __shfl_xor(s2[r], 4);
        s1[r] += __shfl_xor(s1[r], 8);  s2[r] += __shfl_xor(s2[r], 8);
    }
    if (l15 == 0) {
#pragma unroll
        for (int r = 0; r < 4; ++r) {
            red1[w][4 * lg + r] = s1[r];
            red2[w][4 * lg + r] = s2[r];
        }
    }
    __syncthreads();
    if (tid < 16) {
        float t1 = 0.f, t2 = 0.f;
#pragma unroll
        for (int ww = 0; ww < 16; ++ww) { t1 += red1[ww][tid]; t2 += red2[ww][tid]; }
        float mean = t1 * (1.0f / 256.0f);
        float var  = t2 * (1.0f / 256.0f) - mean * mean;
        mrow[tid] = mean;
        irow[tid] = 1.0f / sqrtf(var + 1e-5f);
    }
    __syncthreads();

    const float gv  = ldx(g,  bOff + c, f32);
    const float btv = ldx(bt, bOff + c, f32);
#pragma unroll
    for (int r = 0; r < 4; ++r) {
        int row = 4 * lg + r;
        int tok = m0 + row;
        float out = (v[r] - mrow[row]) * irow[row] * gv + btv;
        if (addpe) out += pe[(size_t)(tok & (LD_ - 1)) * 256 + c];
        size_t idx = (size_t)tok * 256 + c;
        x[idx] = out;
        bf16_t hv = (bf16_t)out;
        xhi[idx] = hv;
        xlo[idx] = (bf16_t)(out - (float)hv);
    }
}

// ---------------------------------------------------------------------------
// Swapped-operand MFMA flash attention, fragment-ready operands, register
// double-buffered, zero LDS/barriers. Emits ctx as pre-split hi/lo bf16.
__global__ __launch_bounds__(256) void fattn4_kernel(
    const bf16_t* __restrict__ Qf, const bf16_t* __restrict__ Kf,
    const bf16_t* __restrict__ Vf,
    bf16_t* __restrict__ Chi, bf16_t* __restrict__ Clo,
    const int* __restrict__ mask, int causal)
{
    const int tid = threadIdx.x;
    const int qt = (int)blockIdx.x ^ ((((int)blockIdx.z >> 1) & 1) << 3);
    const int h = blockIdx.y, b = blockIdx.z;
    const int w = tid >> 6, l = tid & 63, l15 = l & 15, lg = l >> 4;
    const int bh = b * H_ + h;

    const size_t qbase = ((size_t)(bh * 64 + qt * 4 + w)) * 1024 + l * 8;
    const bf16x8 qh = *(const bf16x8*)(Qf + qbase);
    const bf16x8 ql = *(const bf16x8*)(Qf + qbase + 512);
    const int q_global = qt * 64 + w * 16 + l15;

    const bf16_t* kp = Kf + (size_t)bh * 64 * 1024 + l * 8;
    const bf16_t* vp = Vf + (size_t)bh * 16 * 2048 + l * 8;
    const int*    mp = mask + b * 1024 + 4 * lg;

    float m = -3.0e38f, lsum = 0.0f;
    f32x4 o0 = {0.f, 0.f, 0.f, 0.f};
    f32x4 o1 = {0.f, 0.f, 0.f, 0.f};

    const int nkt = causal ? (qt + 1) : (LE_ / 64);

    bf16x8 kha[4], kla[4], vaa[4];  int4 mka[4];
    bf16x8 khb[4], klb[4], vab[4];  int4 mkb[4];

#define FA_LOAD(kh_, kl_, va_, mk_, KT) do {                                    \
    _Pragma("unroll")                                                           \
    for (int nt = 0; nt < 4; ++nt) {                                            \
        kh_[nt] = *(const bf16x8*)(kp + (size_t)(KT) * 4096 + nt * 1024);       \
        kl_[nt] = *(const bf16x8*)(kp + (size_t)(KT) * 4096 + nt * 1024 + 512); \
    }                                                                           \
    va_[0] = *(const bf16x8*)(vp + (size_t)(KT) * 2048);                        \
    va_[1] = *(const bf16x8*)(vp + (size_t)(KT) * 2048 + 1024);                 \
    va_[2] = *(const bf16x8*)(vp + (size_t)(KT) * 2048 + 512);                  \
    va_[3] = *(const bf16x8*)(vp + (size_t)(KT) * 2048 + 1536);                 \
    _Pragma("unroll")                                                           \
    for (int nt = 0; nt < 4; ++nt)                                              \
        mk_[nt] = *(const int4*)(mp + (KT) * 64 + nt * 16);                     \
} while (0)

#define FA_COMPUTE(kh_, kl_, va_, mk_, KT) do {                                 \
    f32x4 s[4];                                                                 \
    _Pragma("unroll")                                                           \
    for (int nt = 0; nt < 4; ++nt) {                                            \
        f32x4 acc = {0.f, 0.f, 0.f, 0.f};                                       \
        acc = __builtin_amdgcn_mfma_f32_16x16x32_bf16(kh_[nt], qh, acc, 0,0,0); \
        acc = __builtin_amdgcn_mfma_f32_16x16x32_bf16(kl_[nt], qh, acc, 0,0,0); \
        acc = __builtin_amdgcn_mfma_f32_16x16x32_bf16(kh_[nt], ql, acc, 0,0,0); \
        s[nt] = acc;                                                            \
    }                                                                           \
    float pm = -3.0e38f;                                                        \
    _Pragma("unroll")                                                           \
    for (int nt = 0; nt < 4; ++nt) {                                            \
        _Pragma("unroll")                                                       \
        for (int r = 0; r < 4; ++r) {                                           \
            int key = (KT) * 64 + 16 * nt + 4 * lg + r;                         \
            int mv = (r==0)?mk_[nt].x:(r==1)?mk_[nt].y:(r==2)?mk_[nt].z:mk_[nt].w; \
            bool dead = (mv != 0) || (causal && key > q_global);                \
            float v = dead ? -1e30f : s[nt][r];                                 \
            s[nt][r] = v;                                                       \
            pm = fmaxf(pm, v);                                                  \
        }                                                                       \
    }                                                                           \
    pm = fmaxf(pm, __shfl_xor(pm, 16));                                         \
    pm = fmaxf(pm, __shfl_xor(pm, 32));                                         \
    float mnew = fmaxf(m, pm);                                                  \
    float alpha = __expf(m - mnew);                                             \
    m = mnew;                                                                   \
    float psum = 0.f;                                                           \
    _Pragma("unroll")                                                           \
    for (int nt = 0; nt < 4; ++nt) {                                            \
        _Pragma("unroll")                                                       \
        for (int r = 0; r < 4; ++r) {                                           \
            float p = __expf(s[nt][r] - m);                                     \
            s[nt][r] = p;                                                       \
            psum += p;                                                          \
        }                                                                       \
    }                                                                           \
    psum += __shfl_xor(psum, 16);                                               \
    psum += __shfl_xor(psum, 32);                                               \
    lsum = lsum * alpha + psum;                                                 \
    _Pragma("unroll")                                                           \
    for (int r = 0; r < 4; ++r) { o0[r] *= alpha; o1[r] *= alpha; }             \
    bf16x8 pb0, pb1;                                                            \
    _Pragma("unroll")                                                           \
    for (int r = 0; r < 4; ++r) {                                               \
        pb0[r]     = (bf16_t)s[0][r];  pb0[4 + r] = (bf16_t)s[1][r];            \
        pb1[r]     = (bf16_t)s[2][r];  pb1[4 + r] = (bf16_t)s[3][r];            \
    }                                                                           \
    o0 = __builtin_amdgcn_mfma_f32_16x16x32_bf16(va_[0], pb0, o0, 0, 0, 0);     \
    o0 = __builtin_amdgcn_mfma_f32_16x16x32_bf16(va_[1], pb1, o0, 0, 0, 0);     \
    o1 = __builtin_amdgcn_mfma_f32_16x16x32_bf16(va_[2], pb0, o1, 0, 0, 0);     \
    o1 = __builtin_amdgcn_mfma_f32_16x16x32_bf16(va_[3], pb1, o1, 0, 0, 0);     \
} while (0)

    FA_LOAD(kha, kla, vaa, mka, 0);
    int kt = 0;
    for (; kt + 2 <= nkt; kt += 2) {
        FA_LOAD(khb, klb, vab, mkb, kt + 1);
        FA_COMPUTE(kha, kla, vaa, mka, kt);
        if (kt + 2 < nkt) FA_LOAD(kha, kla, vaa, mka, kt + 2);
        FA_COMPUTE(khb, klb, vab, mkb, kt + 1);
    }
    if (kt < nkt) FA_COMPUTE(kha, kla, vaa, mka, kt);

#undef FA_LOAD
#undef FA_COMPUTE

    // ---- epilogue: ctx hi/lo bf16 (q=l15 row, dv=4lg+r / 16+4lg+r) ----
    const float inv = 1.0f / lsum;
    bf16x4 h0, l0, h1, l1;
#pragma unroll
    for (int r = 0; r < 4; ++r) {
        float f0 = o0[r] * inv;
        float f1 = o1[r] * inv;
        bf16_t hv0 = (bf16_t)f0;
        bf16_t hv1 = (bf16_t)f1;
        h0[r] = hv0;  l0[r] = (bf16_t)(f0 - (float)hv0);
        h1[r] = hv1;  l1[r] = (bf16_t)(f1 - (float)hv1);
    }
    const size_t ob = ((size_t)(b * LD_ + q_global)) * 256 + h * DK_ + 4 * lg;
    *(bf16x4*)(Chi + ob)      = h0;
    *(bf16x4*)(Chi + ob + 16) = h1;
    *(bf16x4*)(Clo + ob)      = l0;
    *(bf16x4*)(Clo + ob + 16) = l1;
}

__global__ __launch_bounds__(256) void cast_kernel(
    const float* __restrict__ x, void* __restrict__ out, const int* __restrict__ flag)
{
    int f32 = *flag;
    int i = blockIdx.x * 256 + threadIdx.x;
    if (f32) ((float*)out)[i] = x[i];
    else ((bf16*)out)[i] = __float2bfloat16(x[i]);
}

// ---------------------------------------------------------------------------
extern "C" void kernel_launch(void* const* d_in, const int* in_sizes, int n_in,
                              void* d_out, int out_size, void* d_ws, size_t ws_size,
                              hipStream_t stream)
{
    const void* enc       = d_in[0];
    const void* dec       = d_in[1];
    const int*  enc_masks = (const int*)d_in[2];
    const int*  dec_masks = (const int*)d_in[3];
    const void* W_tgt = d_in[4];
    const void* b_tgt = d_in[5];
    const void* sa_Wq = d_in[6];
    const void* sa_bq = d_in[7];
    const void* sa_Wk = d_in[8];
    const void* sa_bk = d_in[9];
    const void* sa_Wv = d_in[10];
    const void* sa_bv = d_in[11];
    const void* sa_Wo = d_in[12];
    const void* sa_bo = d_in[13];
    const void* sa_ln_g = d_in[14];
    const void* sa_ln_b = d_in[15];
    const void* ca_Wq = d_in[16];
    const void* ca_bq = d_in[17];
    const void* ca_Wk = d_in[18];
    const void* ca_bk = d_in[19];
    const void* ca_Wv = d_in[20];
    const void* ca_bv = d_in[21];
    const void* ca_Wo = d_in[22];
    const void* ca_bo = d_in[23];
    const void* ca_ln_g = d_in[24];
    const void* ca_ln_b = d_in[25];
    const void* ff_W1 = d_in[26];
    const void* ff_b1 = d_in[27];
    const void* ff_W2 = d_in[28];
    const void* ff_b2 = d_in[29];
    const void* ff_ln_g = d_in[30];
    const void* ff_ln_b = d_in[31];

    const size_t M1 = (size_t)NTOK * D_;        // 1M floats
    float* ws = (float*)d_ws;
    float*  x      = ws;                                    // [0,1M) floats
    bf16_t* xhi    = (bf16_t*)(ws + 1 * M1);                // M1E elems
    bf16_t* xlo    = xhi + M1E;                             // [1M,2M)
    bf16_t* ctxhi  = (bf16_t*)(ws + 2 * M1);
    bf16_t* ctxlo  = ctxhi + M1E;                           // [2M,3M)
    bf16_t* enchi  = (bf16_t*)(ws + 3 * M1);
    bf16_t* enclo  = enchi + M1E;                           // [3M,4M)
    bf16_t* hhi    = (bf16_t*)(ws + 4 * M1);                // 4M elems [4M,6M)
    bf16_t* hlo    = (bf16_t*)(ws + 6 * M1);                // [6M,8M)
    bf16_t* qbuf   = (bf16_t*)(ws + 8 * M1);                // 2M elems [8M,9M)
    bf16_t* kbuf   = (bf16_t*)(ws + 9 * M1);                // [9M,10M)
    bf16_t* vtbuf  = (bf16_t*)(ws + 10 * M1);               // 1M elems [10M,10.5M)
    float*  pe     = ws + 10 * M1 + M1 / 2;                 // [10.5M,10.75M)
    int*    flag   = (int*)(ws + 10 * M1 + 3 * M1 / 4);
    bf16_t* Wf     = (bf16_t*)(ws + 11 * M1);               // 2*WTOT elems

    const int nElem = NTOK * D_;                // 1,048,576

    detect_kernel<<<1, 256, 0, stream>>>(enc, flag);
    prep_w_kernel<<<3072, 256, 0, stream>>>(
        sa_Wq, sa_Wk, sa_Wv, sa_Wo, ca_Wq, ca_Wk, ca_Wv, ca_Wo,
        ff_W1, ff_W2, Wf, flag);
    pe_build_kernel<<<(LD_ * D_) / 256, 256, 0, stream>>>(pe);
    embed_kernel<<<nElem / 256, 256, 0, stream>>>(dec, W_tgt, b_tgt, x, xhi, xlo, pe, flag);
    enc_split_kernel<<<nElem / 256, 256, 0, stream>>>(enc, enchi, enclo, flag);

    dim3 gProj(D_ / 64, NTOK / 32, 3);          // (4,128,3)
    dim3 gFF1(DFF_ / 64, NTOK / 32, 1);         // (16,128,1)
    dim3 gAttn(LD_ / 64, H_, B_);               // (16,8,4)

    for (int i = 0; i < NL_; ++i) {
        const size_t LB   = (size_t)i * 1048576;   // layer base in Wf (elements)
        const size_t bOff = (size_t)i * D_;

        // --- self attention ---
        gemmf_kernel<<<gProj, 256, 0, stream>>>(
            xhi, xlo, xhi, xlo, xhi, xlo,
            Wf, LB, 65536, sa_bq, sa_bk, sa_bv, bOff,
            qbuf, kbuf, vtbuf, nullptr, NTOK, D_, D_, 1, 0, flag);
        fattn4_kernel<<<gAttn, 256, 0, stream>>>(qbuf, kbuf, vtbuf, ctxhi, ctxlo, dec_masks, 1);
        gemmln_kernel<<<NTOK / 16, 1024, 0, stream>>>(
            ctxhi, ctxlo, Wf, LB + 3 * 65536, sa_bo, x, xhi, xlo,
            sa_ln_g, sa_ln_b, bOff, D_, pe, 0, flag);

        // --- cross attention (enc lo == 0 in bf16 mode -> aexact) ---
        gemmf_kernel<<<gProj, 256, 0, stream>>>(
            xhi, xlo, enchi, enclo, enchi, enclo,
            Wf, LB + 4 * 65536, 65536, ca_bq, ca_bk, ca_bv, bOff,
            qbuf, kbuf, vtbuf, nullptr, NTOK, D_, D_, 1, 1, flag);
        fattn4_kernel<<<gAttn, 256, 0, stream>>>(qbuf, kbuf, vtbuf, ctxhi, ctxlo, enc_masks, 0);
        gemmln_kernel<<<NTOK / 16, 1024, 0, stream>>>(
            ctxhi, ctxlo, Wf, LB + 7 * 65536, ca_bo, x, xhi, xlo,
            ca_ln_g, ca_ln_b, bOff, D_, pe, 0, flag);

        // --- FFN ---
        gemmf_kernel<<<gFF1, 256, 0, stream>>>(
            xhi, xlo, xhi, xlo, xhi, xlo,
            Wf, LB + 524288, 0, ff_b1, ff_b1, ff_b1, (size_t)i * DFF_,
            hhi, hhi, hhi, hlo, NTOK, DFF_, D_, 2, 0, flag);
        gemmln_kernel<<<NTOK / 16, 1024, 0, stream>>>(
            hhi, hlo, Wf, LB + 786432, ff_b2, x, xhi, xlo,
            ff_ln_g, ff_ln_b, bOff, DFF_, pe, (i < NL_ - 1) ? 1 : 0, flag);
    }

    cast_kernel<<<nElem / 256, 256, 0, stream>>>(x, d_out, flag);
}

// Round 8
// 1332.336 us; speedup vs baseline: 1.0009x; 1.0009x over previous
//
#include <hip/hip_runtime.h>
#include <hip/hip_bf16.h>

#define B_   4
#define LD_  1024
#define LE_  1024
#define D_   256
#define H_   8
#define DK_  32
#define DFF_ 1024
#define NL_  6
#define NTOK (B_ * LD_)   // 4096 decoder tokens; encoder also 4*1024 = 4096
#define M1E  1048576      // NTOK * D_ elements
#define WTOT 6291456      // total weight elements across 6 layers (frag layout)

typedef __hip_bfloat16 bf16;
typedef __bf16 bf16_t;
typedef bf16_t bf16x8 __attribute__((ext_vector_type(8)));
typedef bf16_t bf16x4 __attribute__((ext_vector_type(4)));
typedef float  f32x4  __attribute__((ext_vector_type(4)));

__device__ __forceinline__ float bits2f(unsigned short u) {
    union { unsigned int i; float f; } w; w.i = ((unsigned int)u) << 16; return w.f;
}
// dtype-flexible scalar load from tensor base + element index
__device__ __forceinline__ float ldx(const void* p, size_t i, int f32) {
    if (f32) return ((const float*)p)[i];
    return bits2f(((const unsigned short*)p)[i]);
}

// ---------------------------------------------------------------------------
// Detect input dtype (bf16 vs fp32). flag: 1=fp32, 0=bf16.
__global__ __launch_bounds__(256) void detect_kernel(
    const void* __restrict__ enc, int* __restrict__ flag)
{
    __shared__ int bad;
    if (threadIdx.x == 0) bad = 0;
    __syncthreads();
    const unsigned short* u = (const unsigned short*)enc;
    int b = 0;
    for (int i = threadIdx.x; i < 4096; i += 256) {
        unsigned short e = (u[i] >> 7) & 0xFF;
        if (e >= 142) b = 1;
    }
    if (b) atomicOr(&bad, 1);
    __syncthreads();
    if (threadIdx.x == 0) *flag = bad;
}

// ---------------------------------------------------------------------------
// Convert ALL weights to B-fragment-ready bf16 layout, once per launch.
// (layout doc: see round-7 notes; unchanged)
__global__ __launch_bounds__(256) void prep_w_kernel(
    const void* sWq, const void* sWk, const void* sWv, const void* sWo,
    const void* cWq, const void* cWk, const void* cWv, const void* cWo,
    const void* fW1, const void* fW2,
    bf16_t* __restrict__ Wf, const int* __restrict__ flag)
{
    const int f32 = *flag;
    const int g = blockIdx.x * 256 + threadIdx.x;   // 0..786431 frag-groups
    const int li = g >> 17;
    int r = g & 131071;
    const void* src;
    size_t so;
    int N;
    if (r < 65536) {
        int t = r >> 13; r &= 8191;
        N = 256; so = (size_t)li * 65536;
        if      (t == 0) src = sWq; else if (t == 1) src = sWk;
        else if (t == 2) src = sWv; else if (t == 3) src = sWo;
        else if (t == 4) src = cWq; else if (t == 5) src = cWk;
        else if (t == 6) src = cWv; else             src = cWo;
    } else if (r < 98304) {
        r -= 65536; N = 1024; so = (size_t)li * 262144; src = fW1;
    } else {
        r -= 98304; N = 256;  so = (size_t)li * 262144; src = fW2;
    }
    const int lane = r & 63;
    const int q2 = r >> 6;
    int nb, kb;
    if (N == 256) { nb = q2 & 15; kb = q2 >> 4; }
    else          { nb = q2 & 63; kb = q2 >> 6; }
    const int k = kb * 32 + 8 * (lane >> 4);
    const int n = nb * 16 + (lane & 15);
    const size_t out = (size_t)g * 8;
#pragma unroll
    for (int j = 0; j < 8; ++j) {
        float v = ldx(src, so + (size_t)(k + j) * N + n, f32);
        bf16_t hv = (bf16_t)v;
        Wf[out + j] = hv;
        if (f32) Wf[WTOT + out + j] = (bf16_t)(v - (float)hv);
    }
}

// ---------------------------------------------------------------------------
// build PE table [1024][256] once
__global__ __launch_bounds__(256) void pe_build_kernel(float* __restrict__ pe)
{
    int i = blockIdx.x * 256 + threadIdx.x;     // over LD_*D_ = 262144
    int d = i & (D_ - 1);
    int pos = i >> 8;
    int j = d & 127;
    float inv = powf(10000.0f, -2.0f * (float)j / (float)D_);
    float s = (float)pos * inv;
    pe[i] = (d < 128) ? sinf(s) : cosf(s);
}

// x = embed + PE; also emit pre-split hi/lo bf16 (layer-0 proj A operand)
__global__ __launch_bounds__(256) void embed_kernel(
    const void* __restrict__ dec, const void* __restrict__ Wt,
    const void* __restrict__ bt, float* __restrict__ x,
    bf16_t* __restrict__ xhi, bf16_t* __restrict__ xlo,
    const float* __restrict__ pe, const int* __restrict__ flag)
{
    int f32 = *flag;
    int i = blockIdx.x * 256 + threadIdx.x;     // over NTOK * D_
    int d = i & (D_ - 1);
    int t = i >> 8;
    float a0 = ldx(dec, t * 3 + 0, f32);
    float a1 = ldx(dec, t * 3 + 1, f32);
    float a2 = ldx(dec, t * 3 + 2, f32);
    float v = ldx(bt, d, f32) + a0 * ldx(Wt, 0 * D_ + d, f32)
            + a1 * ldx(Wt, 1 * D_ + d, f32) + a2 * ldx(Wt, 2 * D_ + d, f32)
            + pe[i & (LD_ * D_ - 1)];
    x[i] = v;
    bf16_t hv = (bf16_t)v;
    xhi[i] = hv;
    xlo[i] = (bf16_t)(v - (float)hv);
}

// enc -> pre-split hi/lo bf16 (cross-attn K/V proj A operand)
__global__ __launch_bounds__(256) void enc_split_kernel(
    const void* __restrict__ in, bf16_t* __restrict__ ehi, bf16_t* __restrict__ elo,
    const int* __restrict__ flag)
{
    int f32 = *flag;
    int i = blockIdx.x * 256 + threadIdx.x;
    float v = ldx(in, i, f32);
    bf16_t hv = (bf16_t)v;
    ehi[i] = hv;
    elo[i] = (bf16_t)(v - (float)hv);
}

// ---------------------------------------------------------------------------
// Fragment GEMM, depth-4 software-pipelined, dual accumulator chains.
// C = A @ W + bias. A pre-split hi/lo bf16 [M][K]; W = Wf frags (L2-hot).
// Zero LDS/barriers. BM=32, BN=64, 256 thr = 4 waves (2x2).
// bf16 path: named-slot depth-4 pipeline (12-16 b128 in flight/wave),
// hi-chain and lo-chain accumulate independently, summed in epilogue.
// mode 1: attention-prep epilogue (z0=Q,z1=K,z2=V fragment layouts)
// mode 2: C = relu(..) split to hi/lo bf16 [M][N] (FF1 -> h)
__global__ __launch_bounds__(256) void gemmf_kernel(
    const bf16_t* __restrict__ Ah0, const bf16_t* __restrict__ Al0,
    const bf16_t* __restrict__ Ah1, const bf16_t* __restrict__ Al1,
    const bf16_t* __restrict__ Ah2, const bf16_t* __restrict__ Al2,
    const bf16_t* __restrict__ Wf, size_t wfBase, size_t wzStr,
    const void* __restrict__ b0, const void* __restrict__ b1,
    const void* __restrict__ b2, size_t bOff,
    bf16_t* __restrict__ C0, bf16_t* __restrict__ C1,
    bf16_t* __restrict__ C2, bf16_t* __restrict__ Cl,
    int M, int N, int K, int mode, const int* __restrict__ flag)
{
    const int f32 = *flag;
    const int z = blockIdx.z;
    const bf16_t* Ah = (z == 0) ? Ah0 : (z == 1) ? Ah1 : Ah2;
    const bf16_t* Al = (z == 0) ? Al0 : (z == 1) ? Al1 : Al2;
    const void* bias = (z == 0) ? b0 : (z == 1) ? b1 : b2;
    bf16_t* Cb = (z == 0) ? C0 : (z == 1) ? C1 : C2;

    const int tid = threadIdx.x;
    const int m0 = blockIdx.y * 32, n0 = blockIdx.x * 64;
    const int w = tid >> 6, l = tid & 63, l15 = l & 15, lg = l >> 4;
    const int wr = w >> 1, wc = w & 1;

    const bf16_t* wfp = Wf + wfBase + (size_t)z * wzStr;
    const int nbT = N >> 4;
    const int nb0 = (n0 >> 4) + 2 * wc;

    const bf16_t* ap  = Ah + (size_t)(m0 + 16 * wr + l15) * K + 8 * lg;
    const bf16_t* alp = Al + (size_t)(m0 + 16 * wr + l15) * K + 8 * lg;

    f32x4 acc0 = {0.f, 0.f, 0.f, 0.f};
    f32x4 acc1 = {0.f, 0.f, 0.f, 0.f};
    const int K32 = K >> 5;    // always a multiple of 4 here (8 or 32)

    if (!f32) {
        f32x4 d0 = {0.f, 0.f, 0.f, 0.f};
        f32x4 d1 = {0.f, 0.f, 0.f, 0.f};
        bf16x8 A0, L0, P0, Q0, A1, L1, P1, Q1;
        bf16x8 A2, L2, P2, Q2, A3, L3, P3, Q3;
#define GF_LD(Ax, Lx, Px, Qx, KB) do {                                          \
        Ax = *(const bf16x8*)(ap + (KB) * 32);                                  \
        Lx = *(const bf16x8*)(alp + (KB) * 32);                                 \
        Px = *(const bf16x8*)(wfp + ((size_t)((KB) * nbT + nb0) * 64 + l) * 8); \
        Qx = *(const bf16x8*)(wfp + ((size_t)((KB) * nbT + nb0 + 1) * 64 + l) * 8); \
    } while (0)
#define GF_STEP(Ax, Lx, Px, Qx, KB) do {                                        \
        acc0 = __builtin_amdgcn_mfma_f32_16x16x32_bf16(Ax, Px, acc0, 0, 0, 0);  \
        acc1 = __builtin_amdgcn_mfma_f32_16x16x32_bf16(Ax, Qx, acc1, 0, 0, 0);  \
        d0   = __builtin_amdgcn_mfma_f32_16x16x32_bf16(Lx, Px, d0,   0, 0, 0);  \
        d1   = __builtin_amdgcn_mfma_f32_16x16x32_bf16(Lx, Qx, d1,   0, 0, 0);  \
        if ((KB) + 4 < K32) GF_LD(Ax, Lx, Px, Qx, (KB) + 4);                    \
    } while (0)
        GF_LD(A0, L0, P0, Q0, 0);
        GF_LD(A1, L1, P1, Q1, 1);
        GF_LD(A2, L2, P2, Q2, 2);
        GF_LD(A3, L3, P3, Q3, 3);
        for (int kb = 0; kb < K32; kb += 4) {
            GF_STEP(A0, L0, P0, Q0, kb);
            GF_STEP(A1, L1, P1, Q1, kb + 1);
            GF_STEP(A2, L2, P2, Q2, kb + 2);
            GF_STEP(A3, L3, P3, Q3, kb + 3);
        }
#undef GF_LD
#undef GF_STEP
#pragma unroll
        for (int r = 0; r < 4; ++r) { acc0[r] += d0[r]; acc1[r] += d1[r]; }
    } else {
        const bf16_t* wlp = wfp + WTOT;
        for (int kb = 0; kb < K32; ++kb) {
            bf16x8 ah  = *(const bf16x8*)(ap + kb * 32);
            bf16x8 al8 = *(const bf16x8*)(alp + kb * 32);
            bf16x8 bh0 = *(const bf16x8*)(wfp + ((size_t)(kb * nbT + nb0) * 64 + l) * 8);
            bf16x8 bh1 = *(const bf16x8*)(wfp + ((size_t)(kb * nbT + nb0 + 1) * 64 + l) * 8);
            bf16x8 bl0 = *(const bf16x8*)(wlp + ((size_t)(kb * nbT + nb0) * 64 + l) * 8);
            bf16x8 bl1 = *(const bf16x8*)(wlp + ((size_t)(kb * nbT + nb0 + 1) * 64 + l) * 8);
            acc0 = __builtin_amdgcn_mfma_f32_16x16x32_bf16(ah, bh0, acc0, 0, 0, 0);
            acc0 = __builtin_amdgcn_mfma_f32_16x16x32_bf16(al8, bh0, acc0, 0, 0, 0);
            acc0 = __builtin_amdgcn_mfma_f32_16x16x32_bf16(ah, bl0, acc0, 0, 0, 0);
            acc1 = __builtin_amdgcn_mfma_f32_16x16x32_bf16(ah, bh1, acc1, 0, 0, 0);
            acc1 = __builtin_amdgcn_mfma_f32_16x16x32_bf16(al8, bh1, acc1, 0, 0, 0);
            acc1 = __builtin_amdgcn_mfma_f32_16x16x32_bf16(ah, bl1, acc1, 0, 0, 0);
        }
    }

    // epilogue: C/D layout col=l15, row=4*lg+r
    const int cm = m0 + 16 * wr + 4 * lg;
    const int cn = n0 + 32 * wc + l15;
    const float b0v = ldx(bias, bOff + cn, f32);
    const float b1v = ldx(bias, bOff + cn + 16, f32);
    if (mode == 2) {
#pragma unroll
        for (int r = 0; r < 4; ++r) {
#pragma unroll
            for (int cc = 0; cc < 2; ++cc) {
                float v = (cc == 0 ? acc0[r] : acc1[r]) + (cc == 0 ? b0v : b1v);
                v = fmaxf(v, 0.0f);
                size_t idx = (size_t)(cm + r) * N + cn + 16 * cc;
                bf16_t hv = (bf16_t)v;
                C0[idx] = hv;
                Cl[idx] = (bf16_t)(v - (float)hv);
            }
        }
    } else {
        const float qs = (z == 0) ? 0.17677669529663687f : 1.0f;   // 1/sqrt(32)
#pragma unroll
        for (int r = 0; r < 4; ++r) {
            const int token = cm + r;
#pragma unroll
            for (int cc = 0; cc < 2; ++cc) {
                const int d = cn + 16 * cc;
                const float v = ((cc == 0 ? acc0[r] : acc1[r]) + (cc == 0 ? b0v : b1v)) * qs;
                if (z < 2) {
                    int bb = token >> 10, qw = (token >> 4) & 63, lt = token & 15;
                    int hh = d >> 5, lg2 = (d >> 3) & 3, jj = d & 7;
                    size_t base = ((size_t)((bb * 8 + hh) * 64 + qw)) * 1024
                                + (size_t)(lg2 * 16 + lt) * 8 + jj;
                    bf16_t hv = (bf16_t)v;
                    Cb[base]       = hv;
                    Cb[base + 512] = (bf16_t)(v - (float)hv);
                } else {
                    int bb = token >> 10, ktt = (token >> 6) & 15, c2 = (token >> 5) & 1;
                    int w32 = token & 31;
                    int lg2 = (w32 >> 2) & 3, jj = (w32 >> 4) * 4 + (w32 & 3);
                    int hh = d >> 5, dvh = (d >> 4) & 1, lt = d & 15;
                    size_t base = ((size_t)((bb * 8 + hh) * 16 + ktt)) * 2048
                                + c2 * 1024 + dvh * 512 + (size_t)(lg2 * 16 + lt) * 8 + jj;
                    Cb[base] = (bf16_t)v;
                }
            }
        }
    }
}

// ---------------------------------------------------------------------------
// Fragment GEMM + residual + LayerNorm, depth-4 pipelined, dual chains.
// x = LN(A@W + bias + x)*g + b [+pe]; also emits x hi/lo bf16.
// BM=16, N=256, 1024 thr = 16 waves (wave w owns cols 16w..16w+15).
__global__ __launch_bounds__(1024) void gemmln_kernel(
    const bf16_t* __restrict__ Ah, const bf16_t* __restrict__ Al,
    const bf16_t* __restrict__ Wf, size_t wfBase,
    const void* __restrict__ bias, float* __restrict__ x,
    bf16_t* __restrict__ xhi, bf16_t* __restrict__ xlo,
    const void* __restrict__ g, const void* __restrict__ bt,
    size_t bOff, int K,
    const float* __restrict__ pe, int addpe, const int* __restrict__ flag)
{
    const int f32 = *flag;
    __shared__ float red1[16][16];
    __shared__ float red2[16][16];
    __shared__ float mrow[16], irow[16];

    const int tid = threadIdx.x;
    const int m0 = blockIdx.x * 16;
    const int w = tid >> 6, l = tid & 63, l15 = l & 15, lg = l >> 4;

    const bf16_t* ap  = Ah + (size_t)(m0 + l15) * K + 8 * lg;
    const bf16_t* alp = Al + (size_t)(m0 + l15) * K + 8 * lg;
    const bf16_t* wfp = Wf + wfBase;

    f32x4 acc = {0.f, 0.f, 0.f, 0.f};
    const int K32 = K >> 5;    // 8 or 32, multiple of 4

    if (!f32) {
        f32x4 accB = {0.f, 0.f, 0.f, 0.f};
        bf16x8 A0, L0, B0, A1, L1, B1, A2, L2, B2, A3, L3, B3;
#define GL_LD(Ax, Lx, Bx, KB) do {                                              \
        Ax = *(const bf16x8*)(ap + (KB) * 32);                                  \
        Lx = *(const bf16x8*)(alp + (KB) * 32);                                 \
        Bx = *(const bf16x8*)(wfp + ((size_t)((KB) * 16 + w) * 64 + l) * 8);    \
    } while (0)
#define GL_STEP(Ax, Lx, Bx, KB) do {                                            \
        acc  = __builtin_amdgcn_mfma_f32_16x16x32_bf16(Ax, Bx, acc,  0, 0, 0);  \
        accB = __builtin_amdgcn_mfma_f32_16x16x32_bf16(Lx, Bx, accB, 0, 0, 0);  \
        if ((KB) + 4 < K32) GL_LD(Ax, Lx, Bx, (KB) + 4);                        \
    } while (0)
        GL_LD(A0, L0, B0, 0);
        GL_LD(A1, L1, B1, 1);
        GL_LD(A2, L2, B2, 2);
        GL_LD(A3, L3, B3, 3);
        for (int kb = 0; kb < K32; kb += 4) {
            GL_STEP(A0, L0, B0, kb);
            GL_STEP(A1, L1, B1, kb + 1);
            GL_STEP(A2, L2, B2, kb + 2);
            GL_STEP(A3, L3, B3, kb + 3);
        }
#undef GL_LD
#undef GL_STEP
#pragma unroll
        for (int r = 0; r < 4; ++r) acc[r] += accB[r];
    } else {
        const bf16_t* wlp = wfp + WTOT;
        for (int kb = 0; kb < K32; ++kb) {
            bf16x8 ah  = *(const bf16x8*)(ap + kb * 32);
            bf16x8 al8 = *(const bf16x8*)(alp + kb * 32);
            bf16x8 bh  = *(const bf16x8*)(wfp + ((size_t)(kb * 16 + w) * 64 + l) * 8);
            bf16x8 bl  = *(const bf16x8*)(wlp + ((size_t)(kb * 16 + w) * 64 + l) * 8);
            acc = __builtin_amdgcn_mfma_f32_16x16x32_bf16(ah, bh, acc, 0, 0, 0);
            acc = __builtin_amdgcn_mfma_f32_16x16x32_bf16(al8, bh, acc, 0, 0, 0);
            acc = __builtin_amdgcn_mfma_f32_16x16x32_bf16(ah, bl, acc, 0, 0, 0);
        }
    }

    // ---- v = acc + bias + residual; LN stats (rows 4*lg+r, col c) ----
    const int c = 16 * w + l15;
    const float bv = ldx(bias, bOff + c, f32);
    f32x4 v;
    float s1[4], s2[4];
#pragma unroll
    for (int r = 0; r < 4; ++r) {
        int tok = m0 + 4 * lg + r;
        v[r] = acc[r] + bv + x[(size_t)tok * 256 + c];
        s1[r] = v[r];
        s2[r] = v[r] * v[r];
    }
#pragma unroll
    for (int r = 0; r < 4; ++r) {
        s1[r] += __shfl_xor(s1[r], 1);  s2[r] += __shfl_xor(s2[r], 1);
        s1[r] += __shfl_xor(s1[r], 2);  s2[r] += __shfl_xor(s2[r], 2);
        s1[r] += __shfl_xor(s1[r], 4);  s2[r] += __shfl_xor(s2[r], 4);
        s1[r] += __shfl_xor(s1[r], 8);  s2[r] += __shfl_xor(s2[r], 8);
    }
    if (l15 == 0) {
#pragma unroll
        for (int r = 0; r < 4; ++r) {
            red1[w][4 * lg + r] = s1[r];
            red2[w][4 * lg + r] = s2[r];
        }
    }
    __syncthreads();
    if (tid < 16) {
        float t1 = 0.f, t2 = 0.f;
#pragma unroll
        for (int ww = 0; ww < 16; ++ww) { t1 += red1[ww][tid]; t2 += red2[ww][tid]; }
        float mean = t1 * (1.0f / 256.0f);
        float var  = t2 * (1.0f / 256.0f) - mean * mean;
        mrow[tid] = mean;
        irow[tid] = 1.0f / sqrtf(var + 1e-5f);
    }
    __syncthreads();

    const float gv  = ldx(g,  bOff + c, f32);
    const float btv = ldx(bt, bOff + c, f32);
#pragma unroll
    for (int r = 0; r < 4; ++r) {
        int row = 4 * lg + r;
        int tok = m0 + row;
        float out = (v[r] - mrow[row]) * irow[row] * gv + btv;
        if (addpe) out += pe[(size_t)(tok & (LD_ - 1)) * 256 + c];
        size_t idx = (size_t)tok * 256 + c;
        x[idx] = out;
        bf16_t hv = (bf16_t)out;
        xhi[idx] = hv;
        xlo[idx] = (bf16_t)(out - (float)hv);
    }
}

// ---------------------------------------------------------------------------
// Swapped-operand MFMA flash attention, fragment-ready operands, register
// double-buffered, zero LDS/barriers. Emits ctx as pre-split hi/lo bf16.
__global__ __launch_bounds__(256) void fattn4_kernel(
    const bf16_t* __restrict__ Qf, const bf16_t* __restrict__ Kf,
    const bf16_t* __restrict__ Vf,
    bf16_t* __restrict__ Chi, bf16_t* __restrict__ Clo,
    const int* __restrict__ mask, int causal)
{
    const int tid = threadIdx.x;
    const int qt = (int)blockIdx.x ^ ((((int)blockIdx.z >> 1) & 1) << 3);
    const int h = blockIdx.y, b = blockIdx.z;
    const int w = tid >> 6, l = tid & 63, l15 = l & 15, lg = l >> 4;
    const int bh = b * H_ + h;

    const size_t qbase = ((size_t)(bh * 64 + qt * 4 + w)) * 1024 + l * 8;
    const bf16x8 qh = *(const bf16x8*)(Qf + qbase);
    const bf16x8 ql = *(const bf16x8*)(Qf + qbase + 512);
    const int q_global = qt * 64 + w * 16 + l15;

    const bf16_t* kp = Kf + (size_t)bh * 64 * 1024 + l * 8;
    const bf16_t* vp = Vf + (size_t)bh * 16 * 2048 + l * 8;
    const int*    mp = mask + b * 1024 + 4 * lg;

    float m = -3.0e38f, lsum = 0.0f;
    f32x4 o0 = {0.f, 0.f, 0.f, 0.f};
    f32x4 o1 = {0.f, 0.f, 0.f, 0.f};

    const int nkt = causal ? (qt + 1) : (LE_ / 64);

    bf16x8 kha[4], kla[4], vaa[4];  int4 mka[4];
    bf16x8 khb[4], klb[4], vab[4];  int4 mkb[4];

#define FA_LOAD(kh_, kl_, va_, mk_, KT) do {                                    \
    _Pragma("unroll")                                                           \
    for (int nt = 0; nt < 4; ++nt) {                                            \
        kh_[nt] = *(const bf16x8*)(kp + (size_t)(KT) * 4096 + nt * 1024);       \
        kl_[nt] = *(const bf16x8*)(kp + (size_t)(KT) * 4096 + nt * 1024 + 512); \
    }                                                                           \
    va_[0] = *(const bf16x8*)(vp + (size_t)(KT) * 2048);                        \
    va_[1] = *(const bf16x8*)(vp + (size_t)(KT) * 2048 + 1024);                 \
    va_[2] = *(const bf16x8*)(vp + (size_t)(KT) * 2048 + 512);                  \
    va_[3] = *(const bf16x8*)(vp + (size_t)(KT) * 2048 + 1536);                 \
    _Pragma("unroll")                                                           \
    for (int nt = 0; nt < 4; ++nt)                                              \
        mk_[nt] = *(const int4*)(mp + (KT) * 64 + nt * 16);                     \
} while (0)

#define FA_COMPUTE(kh_, kl_, va_, mk_, KT) do {                                 \
    f32x4 s[4];                                                                 \
    _Pragma("unroll")                                                           \
    for (int nt = 0; nt < 4; ++nt) {                                            \
        f32x4 acc = {0.f, 0.f, 0.f, 0.f};                                       \
        acc = __builtin_amdgcn_mfma_f32_16x16x32_bf16(kh_[nt], qh, acc, 0,0,0); \
        acc = __builtin_amdgcn_mfma_f32_16x16x32_bf16(kl_[nt], qh, acc, 0,0,0); \
        acc = __builtin_amdgcn_mfma_f32_16x16x32_bf16(kh_[nt], ql, acc, 0,0,0); \
        s[nt] = acc;                                                            \
    }                                                                           \
    float pm = -3.0e38f;                                                        \
    _Pragma("unroll")                                                           \
    for (int nt = 0; nt < 4; ++nt) {                                            \
        _Pragma("unroll")                                                       \
        for (int r = 0; r < 4; ++r) {                                           \
            int key = (KT) * 64 + 16 * nt + 4 * lg + r;                         \
            int mv = (r==0)?mk_[nt].x:(r==1)?mk_[nt].y:(r==2)?mk_[nt].z:mk_[nt].w; \
            bool dead = (mv != 0) || (causal && key > q_global);                \
            float v = dead ? -1e30f : s[nt][r];                                 \
            s[nt][r] = v;                                                       \
            pm = fmaxf(pm, v);                                                  \
        }                                                                       \
    }                                                                           \
    pm = fmaxf(pm, __shfl_xor(pm, 16));                                         \
    pm = fmaxf(pm, __shfl_xor(pm, 32));                                         \
    float mnew = fmaxf(m, pm);                                                  \
    float alpha = __expf(m - mnew);                                             \
    m = mnew;                                                                   \
    float psum = 0.f;                                                           \
    _Pragma("unroll")                                                           \
    for (int nt = 0; nt < 4; ++nt) {                                            \
        _Pragma("unroll")                                                       \
        for (int r = 0; r < 4; ++r) {                                           \
            float p = __expf(s[nt][r] - m);                                     \
            s[nt][r] = p;                                                       \
            psum += p;                                                          \
        }                                                                       \
    }                                                                           \
    psum += __shfl_xor(psum, 16);                                               \
    psum += __shfl_xor(psum, 32);                                               \
    lsum = lsum * alpha + psum;                                                 \
    _Pragma("unroll")                                                           \
    for (int r = 0; r < 4; ++r) { o0[r] *= alpha; o1[r] *= alpha; }             \
    bf16x8 pb0, pb1;                                                            \
    _Pragma("unroll")                                                           \
    for (int r = 0; r < 4; ++r) {                                               \
        pb0[r]     = (bf16_t)s[0][r];  pb0[4 + r] = (bf16_t)s[1][r];            \
        pb1[r]     = (bf16_t)s[2][r];  pb1[4 + r] = (bf16_t)s[3][r];            \
    }                                                                           \
    o0 = __builtin_amdgcn_mfma_f32_16x16x32_bf16(va_[0], pb0, o0, 0, 0, 0);     \
    o0 = __builtin_amdgcn_mfma_f32_16x16x32_bf16(va_[1], pb1, o0, 0, 0, 0);     \
    o1 = __builtin_amdgcn_mfma_f32_16x16x32_bf16(va_[2], pb0, o1, 0, 0, 0);     \
    o1 = __builtin_amdgcn_mfma_f32_16x16x32_bf16(va_[3], pb1, o1, 0, 0, 0);     \
} while (0)

    FA_LOAD(kha, kla, vaa, mka, 0);
    int kt = 0;
    for (; kt + 2 <= nkt; kt += 2) {
        FA_LOAD(khb, klb, vab, mkb, kt + 1);
        FA_COMPUTE(kha, kla, vaa, mka, kt);
        if (kt + 2 < nkt) FA_LOAD(kha, kla, vaa, mka, kt + 2);
        FA_COMPUTE(khb, klb, vab, mkb, kt + 1);
    }
    if (kt < nkt) FA_COMPUTE(kha, kla, vaa, mka, kt);

#undef FA_LOAD
#undef FA_COMPUTE

    // ---- epilogue: ctx hi/lo bf16 (q=l15 row, dv=4lg+r / 16+4lg+r) ----
    const float inv = 1.0f / lsum;
    bf16x4 h0, l0, h1, l1;
#pragma unroll
    for (int r = 0; r < 4; ++r) {
        float f0 = o0[r] * inv;
        float f1 = o1[r] * inv;
        bf16_t hv0 = (bf16_t)f0;
        bf16_t hv1 = (bf16_t)f1;
        h0[r] = hv0;  l0[r] = (bf16_t)(f0 - (float)hv0);
        h1[r] = hv1;  l1[r] = (bf16_t)(f1 - (float)hv1);
    }
    const size_t ob = ((size_t)(b * LD_ + q_global)) * 256 + h * DK_ + 4 * lg;
    *(bf16x4*)(Chi + ob)      = h0;
    *(bf16x4*)(Chi + ob + 16) = h1;
    *(bf16x4*)(Clo + ob)      = l0;
    *(bf16x4*)(Clo + ob + 16) = l1;
}

__global__ __launch_bounds__(256) void cast_kernel(
    const float* __restrict__ x, void* __restrict__ out, const int* __restrict__ flag)
{
    int f32 = *flag;
    int i = blockIdx.x * 256 + threadIdx.x;
    if (f32) ((float*)out)[i] = x[i];
    else ((bf16*)out)[i] = __float2bfloat16(x[i]);
}

// ---------------------------------------------------------------------------
extern "C" void kernel_launch(void* const* d_in, const int* in_sizes, int n_in,
                              void* d_out, int out_size, void* d_ws, size_t ws_size,
                              hipStream_t stream)
{
    const void* enc       = d_in[0];
    const void* dec       = d_in[1];
    const int*  enc_masks = (const int*)d_in[2];
    const int*  dec_masks = (const int*)d_in[3];
    const void* W_tgt = d_in[4];
    const void* b_tgt = d_in[5];
    const void* sa_Wq = d_in[6];
    const void* sa_bq = d_in[7];
    const void* sa_Wk = d_in[8];
    const void* sa_bk = d_in[9];
    const void* sa_Wv = d_in[10];
    const void* sa_bv = d_in[11];
    const void* sa_Wo = d_in[12];
    const void* sa_bo = d_in[13];
    const void* sa_ln_g = d_in[14];
    const void* sa_ln_b = d_in[15];
    const void* ca_Wq = d_in[16];
    const void* ca_bq = d_in[17];
    const void* ca_Wk = d_in[18];
    const void* ca_bk = d_in[19];
    const void* ca_Wv = d_in[20];
    const void* ca_bv = d_in[21];
    const void* ca_Wo = d_in[22];
    const void* ca_bo = d_in[23];
    const void* ca_ln_g = d_in[24];
    const void* ca_ln_b = d_in[25];
    const void* ff_W1 = d_in[26];
    const void* ff_b1 = d_in[27];
    const void* ff_W2 = d_in[28];
    const void* ff_b2 = d_in[29];
    const void* ff_ln_g = d_in[30];
    const void* ff_ln_b = d_in[31];

    const size_t M1 = (size_t)NTOK * D_;        // 1M floats
    float* ws = (float*)d_ws;
    float*  x      = ws;                                    // [0,1M) floats
    bf16_t* xhi    = (bf16_t*)(ws + 1 * M1);                // M1E elems
    bf16_t* xlo    = xhi + M1E;                             // [1M,2M)
    bf16_t* ctxhi  = (bf16_t*)(ws + 2 * M1);
    bf16_t* ctxlo  = ctxhi + M1E;                           // [2M,3M)
    bf16_t* enchi  = (bf16_t*)(ws + 3 * M1);
    bf16_t* enclo  = enchi + M1E;                           // [3M,4M)
    bf16_t* hhi    = (bf16_t*)(ws + 4 * M1);                // 4M elems [4M,6M)
    bf16_t* hlo    = (bf16_t*)(ws + 6 * M1);                // [6M,8M)
    bf16_t* qbuf   = (bf16_t*)(ws + 8 * M1);                // 2M elems [8M,9M)
    bf16_t* kbuf   = (bf16_t*)(ws + 9 * M1);                // [9M,10M)
    bf16_t* vtbuf  = (bf16_t*)(ws + 10 * M1);               // 1M elems [10M,10.5M)
    float*  pe     = ws + 10 * M1 + M1 / 2;                 // [10.5M,10.75M)
    int*    flag   = (int*)(ws + 10 * M1 + 3 * M1 / 4);
    bf16_t* Wf     = (bf16_t*)(ws + 11 * M1);               // 2*WTOT elems

    const int nElem = NTOK * D_;                // 1,048,576

    detect_kernel<<<1, 256, 0, stream>>>(enc, flag);
    prep_w_kernel<<<3072, 256, 0, stream>>>(
        sa_Wq, sa_Wk, sa_Wv, sa_Wo, ca_Wq, ca_Wk, ca_Wv, ca_Wo,
        ff_W1, ff_W2, Wf, flag);
    pe_build_kernel<<<(LD_ * D_) / 256, 256, 0, stream>>>(pe);
    embed_kernel<<<nElem / 256, 256, 0, stream>>>(dec, W_tgt, b_tgt, x, xhi, xlo, pe, flag);
    enc_split_kernel<<<nElem / 256, 256, 0, stream>>>(enc, enchi, enclo, flag);

    dim3 gProj(D_ / 64, NTOK / 32, 3);          // (4,128,3)
    dim3 gFF1(DFF_ / 64, NTOK / 32, 1);         // (16,128,1)
    dim3 gAttn(LD_ / 64, H_, B_);               // (16,8,4)

    for (int i = 0; i < NL_; ++i) {
        const size_t LB   = (size_t)i * 1048576;   // layer base in Wf (elements)
        const size_t bOff = (size_t)i * D_;

        // --- self attention ---
        gemmf_kernel<<<gProj, 256, 0, stream>>>(
            xhi, xlo, xhi, xlo, xhi, xlo,
            Wf, LB, 65536, sa_bq, sa_bk, sa_bv, bOff,
            qbuf, kbuf, vtbuf, nullptr, NTOK, D_, D_, 1, flag);
        fattn4_kernel<<<gAttn, 256, 0, stream>>>(qbuf, kbuf, vtbuf, ctxhi, ctxlo, dec_masks, 1);
        gemmln_kernel<<<NTOK / 16, 1024, 0, stream>>>(
            ctxhi, ctxlo, Wf, LB + 3 * 65536, sa_bo, x, xhi, xlo,
            sa_ln_g, sa_ln_b, bOff, D_, pe, 0, flag);

        // --- cross attention ---
        gemmf_kernel<<<gProj, 256, 0, stream>>>(
            xhi, xlo, enchi, enclo, enchi, enclo,
            Wf, LB + 4 * 65536, 65536, ca_bq, ca_bk, ca_bv, bOff,
            qbuf, kbuf, vtbuf, nullptr, NTOK, D_, D_, 1, flag);
        fattn4_kernel<<<gAttn, 256, 0, stream>>>(qbuf, kbuf, vtbuf, ctxhi, ctxlo, enc_masks, 0);
        gemmln_kernel<<<NTOK / 16, 1024, 0, stream>>>(
            ctxhi, ctxlo, Wf, LB + 7 * 65536, ca_bo, x, xhi, xlo,
            ca_ln_g, ca_ln_b, bOff, D_, pe, 0, flag);

        // --- FFN ---
        gemmf_kernel<<<gFF1, 256, 0, stream>>>(
            xhi, xlo, xhi, xlo, xhi, xlo,
            Wf, LB + 524288, 0, ff_b1, ff_b1, ff_b1, (size_t)i * DFF_,
            hhi, hhi, hhi, hlo, NTOK, DFF_, D_, 2, flag);
        gemmln_kernel<<<NTOK / 16, 1024, 0, stream>>>(
            hhi, hlo, Wf, LB + 786432, ff_b2, x, xhi, xlo,
            ff_ln_g, ff_ln_b, bOff, DFF_, pe, (i < NL_ - 1) ? 1 : 0, flag);
    }

    cast_kernel<<<nElem / 256, 256, 0, stream>>>(x, d_out, flag);
}

// Round 9
// 1040.649 us; speedup vs baseline: 1.2814x; 1.2803x over previous
//
#include <hip/hip_runtime.h>
#include <hip/hip_bf16.h>

#define B_   4
#define LD_  1024
#define LE_  1024
#define D_   256
#define H_   8
#define DK_  32
#define DFF_ 1024
#define NL_  6
#define NTOK (B_ * LD_)   // 4096 decoder tokens; encoder also 4*1024 = 4096
#define M1E  1048576      // NTOK * D_ elements
#define WTOT 6291456      // total weight elements across 6 layers (frag layout)

typedef __hip_bfloat16 bf16;
typedef __bf16 bf16_t;
typedef bf16_t bf16x8 __attribute__((ext_vector_type(8)));
typedef bf16_t bf16x4 __attribute__((ext_vector_type(4)));
typedef float  f32x4  __attribute__((ext_vector_type(4)));

__device__ __forceinline__ float bits2f(unsigned short u) {
    union { unsigned int i; float f; } w; w.i = ((unsigned int)u) << 16; return w.f;
}
// dtype-flexible scalar load from tensor base + element index
__device__ __forceinline__ float ldx(const void* p, size_t i, int f32) {
    if (f32) return ((const float*)p)[i];
    return bits2f(((const unsigned short*)p)[i]);
}
// A-fragment index: element (m,k) of an [M][K] matrix, K32 = K/32.
// group = ((m>>4)*K32 + (k>>5))*64 + ((k>>3)&3)*16 + (m&15); elem j = k&7.
__device__ __forceinline__ size_t afrag_idx(int m, int k, int K32) {
    return ((((size_t)(m >> 4) * K32 + (k >> 5)) * 64
             + (size_t)(((k >> 3) & 3) * 16 + (m & 15))) << 3) + (k & 7);
}

// ---------------------------------------------------------------------------
// Detect input dtype (bf16 vs fp32). flag: 1=fp32, 0=bf16.
__global__ __launch_bounds__(256) void detect_kernel(
    const void* __restrict__ enc, int* __restrict__ flag)
{
    __shared__ int bad;
    if (threadIdx.x == 0) bad = 0;
    __syncthreads();
    const unsigned short* u = (const unsigned short*)enc;
    int b = 0;
    for (int i = threadIdx.x; i < 4096; i += 256) {
        unsigned short e = (u[i] >> 7) & 0xFF;
        if (e >= 142) b = 1;
    }
    if (b) atomicOr(&bad, 1);
    __syncthreads();
    if (threadIdx.x == 0) *flag = bad;
}

// ---------------------------------------------------------------------------
// Convert ALL weights to B-fragment-ready bf16 layout, once per launch.
// (layout doc: see round-7 notes; unchanged)
__global__ __launch_bounds__(256) void prep_w_kernel(
    const void* sWq, const void* sWk, const void* sWv, const void* sWo,
    const void* cWq, const void* cWk, const void* cWv, const void* cWo,
    const void* fW1, const void* fW2,
    bf16_t* __restrict__ Wf, const int* __restrict__ flag)
{
    const int f32 = *flag;
    const int g = blockIdx.x * 256 + threadIdx.x;   // 0..786431 frag-groups
    const int li = g >> 17;
    int r = g & 131071;
    const void* src;
    size_t so;
    int N;
    if (r < 65536) {
        int t = r >> 13; r &= 8191;
        N = 256; so = (size_t)li * 65536;
        if      (t == 0) src = sWq; else if (t == 1) src = sWk;
        else if (t == 2) src = sWv; else if (t == 3) src = sWo;
        else if (t == 4) src = cWq; else if (t == 5) src = cWk;
        else if (t == 6) src = cWv; else             src = cWo;
    } else if (r < 98304) {
        r -= 65536; N = 1024; so = (size_t)li * 262144; src = fW1;
    } else {
        r -= 98304; N = 256;  so = (size_t)li * 262144; src = fW2;
    }
    const int lane = r & 63;
    const int q2 = r >> 6;
    int nb, kb;
    if (N == 256) { nb = q2 & 15; kb = q2 >> 4; }
    else          { nb = q2 & 63; kb = q2 >> 6; }
    const int k = kb * 32 + 8 * (lane >> 4);
    const int n = nb * 16 + (lane & 15);
    const size_t out = (size_t)g * 8;
#pragma unroll
    for (int j = 0; j < 8; ++j) {
        float v = ldx(src, so + (size_t)(k + j) * N + n, f32);
        bf16_t hv = (bf16_t)v;
        Wf[out + j] = hv;
        if (f32) Wf[WTOT + out + j] = (bf16_t)(v - (float)hv);
    }
}

// ---------------------------------------------------------------------------
// build PE table [1024][256] once
__global__ __launch_bounds__(256) void pe_build_kernel(float* __restrict__ pe)
{
    int i = blockIdx.x * 256 + threadIdx.x;     // over LD_*D_ = 262144
    int d = i & (D_ - 1);
    int pos = i >> 8;
    int j = d & 127;
    float inv = powf(10000.0f, -2.0f * (float)j / (float)D_);
    float s = (float)pos * inv;
    pe[i] = (d < 128) ? sinf(s) : cosf(s);
}

// x = embed + PE; fp32 row-major + hi/lo bf16 in A-frag layout (K=256)
__global__ __launch_bounds__(256) void embed_kernel(
    const void* __restrict__ dec, const void* __restrict__ Wt,
    const void* __restrict__ bt, float* __restrict__ x,
    bf16_t* __restrict__ xhi, bf16_t* __restrict__ xlo,
    const float* __restrict__ pe, const int* __restrict__ flag)
{
    int f32 = *flag;
    int i = blockIdx.x * 256 + threadIdx.x;     // over NTOK * D_
    int d = i & (D_ - 1);
    int t = i >> 8;
    float a0 = ldx(dec, t * 3 + 0, f32);
    float a1 = ldx(dec, t * 3 + 1, f32);
    float a2 = ldx(dec, t * 3 + 2, f32);
    float v = ldx(bt, d, f32) + a0 * ldx(Wt, 0 * D_ + d, f32)
            + a1 * ldx(Wt, 1 * D_ + d, f32) + a2 * ldx(Wt, 2 * D_ + d, f32)
            + pe[i & (LD_ * D_ - 1)];
    x[i] = v;
    size_t fi = afrag_idx(t, d, 8);
    bf16_t hv = (bf16_t)v;
    xhi[fi] = hv;
    xlo[fi] = (bf16_t)(v - (float)hv);
}

// enc -> hi/lo bf16 in A-frag layout (K=256)
__global__ __launch_bounds__(256) void enc_split_kernel(
    const void* __restrict__ in, bf16_t* __restrict__ ehi, bf16_t* __restrict__ elo,
    const int* __restrict__ flag)
{
    int f32 = *flag;
    int i = blockIdx.x * 256 + threadIdx.x;
    int d = i & (D_ - 1);
    int t = i >> 8;
    float v = ldx(in, i, f32);
    size_t fi = afrag_idx(t, d, 8);
    bf16_t hv = (bf16_t)v;
    ehi[fi] = hv;
    elo[fi] = (bf16_t)(v - (float)hv);
}

// ---------------------------------------------------------------------------
// Fragment GEMM, depth-4 software-pipelined, dual accumulator chains.
// C = A @ W + bias. A hi/lo bf16 in A-FRAG layout (1KB coalesced loads);
// W = Wf frags (L2-hot). Zero LDS/barriers. BM=32, BN=64, 4 waves (2x2).
// mode 1: attention-prep epilogue (z0=Q,z1=K,z2=V fragment layouts)
// mode 2: C = relu(..) -> h hi/lo in A-frag layout (K32=32)
__global__ __launch_bounds__(256) void gemmf_kernel(
    const bf16_t* __restrict__ Ah0, const bf16_t* __restrict__ Al0,
    const bf16_t* __restrict__ Ah1, const bf16_t* __restrict__ Al1,
    const bf16_t* __restrict__ Ah2, const bf16_t* __restrict__ Al2,
    const bf16_t* __restrict__ Wf, size_t wfBase, size_t wzStr,
    const void* __restrict__ b0, const void* __restrict__ b1,
    const void* __restrict__ b2, size_t bOff,
    bf16_t* __restrict__ C0, bf16_t* __restrict__ C1,
    bf16_t* __restrict__ C2, bf16_t* __restrict__ Cl,
    int M, int N, int K, int mode, const int* __restrict__ flag)
{
    const int f32 = *flag;
    const int z = blockIdx.z;
    const bf16_t* Ah = (z == 0) ? Ah0 : (z == 1) ? Ah1 : Ah2;
    const bf16_t* Al = (z == 0) ? Al0 : (z == 1) ? Al1 : Al2;
    const void* bias = (z == 0) ? b0 : (z == 1) ? b1 : b2;
    bf16_t* Cb = (z == 0) ? C0 : (z == 1) ? C1 : C2;

    const int tid = threadIdx.x;
    const int m0 = blockIdx.y * 32, n0 = blockIdx.x * 64;
    const int w = tid >> 6, l = tid & 63, l15 = l & 15, lg = l >> 4;
    const int wr = w >> 1, wc = w & 1;

    const bf16_t* wfp = Wf + wfBase + (size_t)z * wzStr;
    const int nbT = N >> 4;
    const int nb0 = (n0 >> 4) + 2 * wc;
    const int K32 = K >> 5;    // 8 or 32, multiple of 4

    const int mb = (m0 >> 4) + wr;
    const bf16_t* ap  = Ah + ((size_t)mb * K32 * 64 + l) * 8;
    const bf16_t* alp = Al + ((size_t)mb * K32 * 64 + l) * 8;

    f32x4 acc0 = {0.f, 0.f, 0.f, 0.f};
    f32x4 acc1 = {0.f, 0.f, 0.f, 0.f};

    if (!f32) {
        f32x4 d0 = {0.f, 0.f, 0.f, 0.f};
        f32x4 d1 = {0.f, 0.f, 0.f, 0.f};
        bf16x8 A0, L0, P0, Q0, A1, L1, P1, Q1;
        bf16x8 A2, L2, P2, Q2, A3, L3, P3, Q3;
#define GF_LD(Ax, Lx, Px, Qx, KB) do {                                          \
        Ax = *(const bf16x8*)(ap + (size_t)(KB) * 512);                         \
        Lx = *(const bf16x8*)(alp + (size_t)(KB) * 512);                        \
        Px = *(const bf16x8*)(wfp + ((size_t)((KB) * nbT + nb0) * 64 + l) * 8); \
        Qx = *(const bf16x8*)(wfp + ((size_t)((KB) * nbT + nb0 + 1) * 64 + l) * 8); \
    } while (0)
#define GF_STEP(Ax, Lx, Px, Qx, KB) do {                                        \
        acc0 = __builtin_amdgcn_mfma_f32_16x16x32_bf16(Ax, Px, acc0, 0, 0, 0);  \
        acc1 = __builtin_amdgcn_mfma_f32_16x16x32_bf16(Ax, Qx, acc1, 0, 0, 0);  \
        d0   = __builtin_amdgcn_mfma_f32_16x16x32_bf16(Lx, Px, d0,   0, 0, 0);  \
        d1   = __builtin_amdgcn_mfma_f32_16x16x32_bf16(Lx, Qx, d1,   0, 0, 0);  \
        if ((KB) + 4 < K32) GF_LD(Ax, Lx, Px, Qx, (KB) + 4);                    \
    } while (0)
        GF_LD(A0, L0, P0, Q0, 0);
        GF_LD(A1, L1, P1, Q1, 1);
        GF_LD(A2, L2, P2, Q2, 2);
        GF_LD(A3, L3, P3, Q3, 3);
        for (int kb = 0; kb < K32; kb += 4) {
            GF_STEP(A0, L0, P0, Q0, kb);
            GF_STEP(A1, L1, P1, Q1, kb + 1);
            GF_STEP(A2, L2, P2, Q2, kb + 2);
            GF_STEP(A3, L3, P3, Q3, kb + 3);
        }
#undef GF_LD
#undef GF_STEP
#pragma unroll
        for (int r = 0; r < 4; ++r) { acc0[r] += d0[r]; acc1[r] += d1[r]; }
    } else {
        const bf16_t* wlp = wfp + WTOT;
        for (int kb = 0; kb < K32; ++kb) {
            bf16x8 ah  = *(const bf16x8*)(ap + (size_t)kb * 512);
            bf16x8 al8 = *(const bf16x8*)(alp + (size_t)kb * 512);
            bf16x8 bh0 = *(const bf16x8*)(wfp + ((size_t)(kb * nbT + nb0) * 64 + l) * 8);
            bf16x8 bh1 = *(const bf16x8*)(wfp + ((size_t)(kb * nbT + nb0 + 1) * 64 + l) * 8);
            bf16x8 bl0 = *(const bf16x8*)(wlp + ((size_t)(kb * nbT + nb0) * 64 + l) * 8);
            bf16x8 bl1 = *(const bf16x8*)(wlp + ((size_t)(kb * nbT + nb0 + 1) * 64 + l) * 8);
            acc0 = __builtin_amdgcn_mfma_f32_16x16x32_bf16(ah, bh0, acc0, 0, 0, 0);
            acc0 = __builtin_amdgcn_mfma_f32_16x16x32_bf16(al8, bh0, acc0, 0, 0, 0);
            acc0 = __builtin_amdgcn_mfma_f32_16x16x32_bf16(ah, bl0, acc0, 0, 0, 0);
            acc1 = __builtin_amdgcn_mfma_f32_16x16x32_bf16(ah, bh1, acc1, 0, 0, 0);
            acc1 = __builtin_amdgcn_mfma_f32_16x16x32_bf16(al8, bh1, acc1, 0, 0, 0);
            acc1 = __builtin_amdgcn_mfma_f32_16x16x32_bf16(ah, bl1, acc1, 0, 0, 0);
        }
    }

    // epilogue: C/D layout col=l15, row=4*lg+r
    const int cm = m0 + 16 * wr + 4 * lg;
    const int cn = n0 + 32 * wc + l15;
    const float b0v = ldx(bias, bOff + cn, f32);
    const float b1v = ldx(bias, bOff + cn + 16, f32);
    if (mode == 2) {
#pragma unroll
        for (int r = 0; r < 4; ++r) {
#pragma unroll
            for (int cc = 0; cc < 2; ++cc) {
                float v = (cc == 0 ? acc0[r] : acc1[r]) + (cc == 0 ? b0v : b1v);
                v = fmaxf(v, 0.0f);
                size_t fi = afrag_idx(cm + r, cn + 16 * cc, 32);
                bf16_t hv = (bf16_t)v;
                C0[fi] = hv;
                Cl[fi] = (bf16_t)(v - (float)hv);
            }
        }
    } else {
        const float qs = (z == 0) ? 0.17677669529663687f : 1.0f;   // 1/sqrt(32)
#pragma unroll
        for (int r = 0; r < 4; ++r) {
            const int token = cm + r;
#pragma unroll
            for (int cc = 0; cc < 2; ++cc) {
                const int d = cn + 16 * cc;
                const float v = ((cc == 0 ? acc0[r] : acc1[r]) + (cc == 0 ? b0v : b1v)) * qs;
                if (z < 2) {
                    int bb = token >> 10, qw = (token >> 4) & 63, lt = token & 15;
                    int hh = d >> 5, lg2 = (d >> 3) & 3, jj = d & 7;
                    size_t base = ((size_t)((bb * 8 + hh) * 64 + qw)) * 1024
                                + (size_t)(lg2 * 16 + lt) * 8 + jj;
                    bf16_t hv = (bf16_t)v;
                    Cb[base]       = hv;
                    Cb[base + 512] = (bf16_t)(v - (float)hv);
                } else {
                    int bb = token >> 10, ktt = (token >> 6) & 15, c2 = (token >> 5) & 1;
                    int w32 = token & 31;
                    int lg2 = (w32 >> 2) & 3, jj = (w32 >> 4) * 4 + (w32 & 3);
                    int hh = d >> 5, dvh = (d >> 4) & 1, lt = d & 15;
                    size_t base = ((size_t)((bb * 8 + hh) * 16 + ktt)) * 2048
                                + c2 * 1024 + dvh * 512 + (size_t)(lg2 * 16 + lt) * 8 + jj;
                    Cb[base] = (bf16_t)v;
                }
            }
        }
    }
}

// ---------------------------------------------------------------------------
// Fragment GEMM + residual + LayerNorm, depth-4 pipelined, dual chains.
// x = LN(A@W + bias + x)*g + b [+pe]; emits x hi/lo in A-frag layout.
// A in A-frag layout (1KB coalesced loads, L1-broadcast across 16 waves).
// BM=16, N=256, 1024 thr = 16 waves (wave w owns cols 16w..16w+15).
__global__ __launch_bounds__(1024) void gemmln_kernel(
    const bf16_t* __restrict__ Ah, const bf16_t* __restrict__ Al,
    const bf16_t* __restrict__ Wf, size_t wfBase,
    const void* __restrict__ bias, float* __restrict__ x,
    bf16_t* __restrict__ xhi, bf16_t* __restrict__ xlo,
    const void* __restrict__ g, const void* __restrict__ bt,
    size_t bOff, int K,
    const float* __restrict__ pe, int addpe, const int* __restrict__ flag)
{
    const int f32 = *flag;
    __shared__ float red1[16][16];
    __shared__ float red2[16][16];
    __shared__ float mrow[16], irow[16];

    const int tid = threadIdx.x;
    const int m0 = blockIdx.x * 16;
    const int w = tid >> 6, l = tid & 63, l15 = l & 15, lg = l >> 4;
    const int K32 = K >> 5;    // 8 or 32, multiple of 4

    const bf16_t* ap  = Ah + ((size_t)blockIdx.x * K32 * 64 + l) * 8;
    const bf16_t* alp = Al + ((size_t)blockIdx.x * K32 * 64 + l) * 8;
    const bf16_t* wfp = Wf + wfBase;

    f32x4 acc = {0.f, 0.f, 0.f, 0.f};

    if (!f32) {
        f32x4 accB = {0.f, 0.f, 0.f, 0.f};
        bf16x8 A0, L0, B0, A1, L1, B1, A2, L2, B2, A3, L3, B3;
#define GL_LD(Ax, Lx, Bx, KB) do {                                              \
        Ax = *(const bf16x8*)(ap + (size_t)(KB) * 512);                         \
        Lx = *(const bf16x8*)(alp + (size_t)(KB) * 512);                        \
        Bx = *(const bf16x8*)(wfp + ((size_t)((KB) * 16 + w) * 64 + l) * 8);    \
    } while (0)
#define GL_STEP(Ax, Lx, Bx, KB) do {                                            \
        acc  = __builtin_amdgcn_mfma_f32_16x16x32_bf16(Ax, Bx, acc,  0, 0, 0);  \
        accB = __builtin_amdgcn_mfma_f32_16x16x32_bf16(Lx, Bx, accB, 0, 0, 0);  \
        if ((KB) + 4 < K32) GL_LD(Ax, Lx, Bx, (KB) + 4);                        \
    } while (0)
        GL_LD(A0, L0, B0, 0);
        GL_LD(A1, L1, B1, 1);
        GL_LD(A2, L2, B2, 2);
        GL_LD(A3, L3, B3, 3);
        for (int kb = 0; kb < K32; kb += 4) {
            GL_STEP(A0, L0, B0, kb);
            GL_STEP(A1, L1, B1, kb + 1);
            GL_STEP(A2, L2, B2, kb + 2);
            GL_STEP(A3, L3, B3, kb + 3);
        }
#undef GL_LD
#undef GL_STEP
#pragma unroll
        for (int r = 0; r < 4; ++r) acc[r] += accB[r];
    } else {
        const bf16_t* wlp = wfp + WTOT;
        for (int kb = 0; kb < K32; ++kb) {
            bf16x8 ah  = *(const bf16x8*)(ap + (size_t)kb * 512);
            bf16x8 al8 = *(const bf16x8*)(alp + (size_t)kb * 512);
            bf16x8 bh  = *(const bf16x8*)(wfp + ((size_t)(kb * 16 + w) * 64 + l) * 8);
            bf16x8 bl  = *(const bf16x8*)(wlp + ((size_t)(kb * 16 + w) * 64 + l) * 8);
            acc = __builtin_amdgcn_mfma_f32_16x16x32_bf16(ah, bh, acc, 0, 0, 0);
            acc = __builtin_amdgcn_mfma_f32_16x16x32_bf16(al8, bh, acc, 0, 0, 0);
            acc = __builtin_amdgcn_mfma_f32_16x16x32_bf16(ah, bl, acc, 0, 0, 0);
        }
    }

    // ---- v = acc + bias + residual; LN stats (rows 4*lg+r, col c) ----
    const int c = 16 * w + l15;
    const float bv = ldx(bias, bOff + c, f32);
    f32x4 v;
    float s1[4], s2[4];
#pragma unroll
    for (int r = 0; r < 4; ++r) {
        int tok = m0 + 4 * lg + r;
        v[r] = acc[r] + bv + x[(size_t)tok * 256 + c];
        s1[r] = v[r];
        s2[r] = v[r] * v[r];
    }
#pragma unroll
    for (int r = 0; r < 4; ++r) {
        s1[r] += __shfl_xor(s1[r], 1);  s2[r] += __shfl_xor(s2[r], 1);
        s1[r] += __shfl_xor(s1[r], 2);  s2[r] += __shfl_xor(s2[r], 2);
        s1[r] += __shfl_xor(s1[r], 4);  s2[r] += __shfl_xor(s2[r], 4);
        s1[r] += __shfl_xor(s1[r], 8);  s2[r] += __shfl_xor(s2[r], 8);
    }
    if (l15 == 0) {
#pragma unroll
        for (int r = 0; r < 4; ++r) {
            red1[w][4 * lg + r] = s1[r];
            red2[w][4 * lg + r] = s2[r];
        }
    }
    __syncthreads();
    if (tid < 16) {
        float t1 = 0.f, t2 = 0.f;
#pragma unroll
        for (int ww = 0; ww < 16; ++ww) { t1 += red1[ww][tid]; t2 += red2[ww][tid]; }
        float mean = t1 * (1.0f / 256.0f);
        float var  = t2 * (1.0f / 256.0f) - mean * mean;
        mrow[tid] = mean;
        irow[tid] = 1.0f / sqrtf(var + 1e-5f);
    }
    __syncthreads();

    const float gv  = ldx(g,  bOff + c, f32);
    const float btv = ldx(bt, bOff + c, f32);
#pragma unroll
    for (int r = 0; r < 4; ++r) {
        int row = 4 * lg + r;
        int tok = m0 + row;
        float out = (v[r] - mrow[row]) * irow[row] * gv + btv;
        if (addpe) out += pe[(size_t)(tok & (LD_ - 1)) * 256 + c];
        x[(size_t)tok * 256 + c] = out;
        size_t fi = afrag_idx(tok, c, 8);
        bf16_t hv = (bf16_t)out;
        xhi[fi] = hv;
        xlo[fi] = (bf16_t)(out - (float)hv);
    }
}

// ---------------------------------------------------------------------------
// Swapped-operand MFMA flash attention, fragment-ready operands, register
// double-buffered, zero LDS/barriers. Emits ctx hi/lo in A-FRAG layout
// (K=256, kb = head index) for the Wo gemmln.
__global__ __launch_bounds__(256) void fattn4_kernel(
    const bf16_t* __restrict__ Qf, const bf16_t* __restrict__ Kf,
    const bf16_t* __restrict__ Vf,
    bf16_t* __restrict__ Chi, bf16_t* __restrict__ Clo,
    const int* __restrict__ mask, int causal)
{
    const int tid = threadIdx.x;
    const int qt = (int)blockIdx.x ^ ((((int)blockIdx.z >> 1) & 1) << 3);
    const int h = blockIdx.y, b = blockIdx.z;
    const int w = tid >> 6, l = tid & 63, l15 = l & 15, lg = l >> 4;
    const int bh = b * H_ + h;

    const size_t qbase = ((size_t)(bh * 64 + qt * 4 + w)) * 1024 + l * 8;
    const bf16x8 qh = *(const bf16x8*)(Qf + qbase);
    const bf16x8 ql = *(const bf16x8*)(Qf + qbase + 512);
    const int q_global = qt * 64 + w * 16 + l15;

    const bf16_t* kp = Kf + (size_t)bh * 64 * 1024 + l * 8;
    const bf16_t* vp = Vf + (size_t)bh * 16 * 2048 + l * 8;
    const int*    mp = mask + b * 1024 + 4 * lg;

    float m = -3.0e38f, lsum = 0.0f;
    f32x4 o0 = {0.f, 0.f, 0.f, 0.f};
    f32x4 o1 = {0.f, 0.f, 0.f, 0.f};

    const int nkt = causal ? (qt + 1) : (LE_ / 64);

    bf16x8 kha[4], kla[4], vaa[4];  int4 mka[4];
    bf16x8 khb[4], klb[4], vab[4];  int4 mkb[4];

#define FA_LOAD(kh_, kl_, va_, mk_, KT) do {                                    \
    _Pragma("unroll")                                                           \
    for (int nt = 0; nt < 4; ++nt) {                                            \
        kh_[nt] = *(const bf16x8*)(kp + (size_t)(KT) * 4096 + nt * 1024);       \
        kl_[nt] = *(const bf16x8*)(kp + (size_t)(KT) * 4096 + nt * 1024 + 512); \
    }                                                                           \
    va_[0] = *(const bf16x8*)(vp + (size_t)(KT) * 2048);                        \
    va_[1] = *(const bf16x8*)(vp + (size_t)(KT) * 2048 + 1024);                 \
    va_[2] = *(const bf16x8*)(vp + (size_t)(KT) * 2048 + 512);                  \
    va_[3] = *(const bf16x8*)(vp + (size_t)(KT) * 2048 + 1536);                 \
    _Pragma("unroll")                                                           \
    for (int nt = 0; nt < 4; ++nt)                                              \
        mk_[nt] = *(const int4*)(mp + (KT) * 64 + nt * 16);                     \
} while (0)

#define FA_COMPUTE(kh_, kl_, va_, mk_, KT) do {                                 \
    f32x4 s[4];                                                                 \
    _Pragma("unroll")                                                           \
    for (int nt = 0; nt < 4; ++nt) {                                            \
        f32x4 acc = {0.f, 0.f, 0.f, 0.f};                                       \
        acc = __builtin_amdgcn_mfma_f32_16x16x32_bf16(kh_[nt], qh, acc, 0,0,0); \
        acc = __builtin_amdgcn_mfma_f32_16x16x32_bf16(kl_[nt], qh, acc, 0,0,0); \
        acc = __builtin_amdgcn_mfma_f32_16x16x32_bf16(kh_[nt], ql, acc, 0,0,0); \
        s[nt] = acc;                                                            \
    }                                                                           \
    float pm = -3.0e38f;                                                        \
    _Pragma("unroll")                                                           \
    for (int nt = 0; nt < 4; ++nt) {                                            \
        _Pragma("unroll")                                                       \
        for (int r = 0; r < 4; ++r) {                                           \
            int key = (KT) * 64 + 16 * nt + 4 * lg + r;                         \
            int mv = (r==0)?mk_[nt].x:(r==1)?mk_[nt].y:(r==2)?mk_[nt].z:mk_[nt].w; \
            bool dead = (mv != 0) || (causal && key > q_global);                \
            float v = dead ? -1e30f : s[nt][r];                                 \
            s[nt][r] = v;                                                       \
            pm = fmaxf(pm, v);                                                  \
        }                                                                       \
    }                                                                           \
    pm = fmaxf(pm, __shfl_xor(pm, 16));                                         \
    pm = fmaxf(pm, __shfl_xor(pm, 32));                                         \
    float mnew = fmaxf(m, pm);                                                  \
    float alpha = __expf(m - mnew);                                             \
    m = mnew;                                                                   \
    float psum = 0.f;                                                           \
    _Pragma("unroll")                                                           \
    for (int nt = 0; nt < 4; ++nt) {                                            \
        _Pragma("unroll")                                                       \
        for (int r = 0; r < 4; ++r) {                                           \
            float p = __expf(s[nt][r] - m);                                     \
            s[nt][r] = p;                                                       \
            psum += p;                                                          \
        }                                                                       \
    }                                                                           \
    psum += __shfl_xor(psum, 16);                                               \
    psum += __shfl_xor(psum, 32);                                               \
    lsum = lsum * alpha + psum;                                                 \
    _Pragma("unroll")                                                           \
    for (int r = 0; r < 4; ++r) { o0[r] *= alpha; o1[r] *= alpha; }             \
    bf16x8 pb0, pb1;                                                            \
    _Pragma("unroll")                                                           \
    for (int r = 0; r < 4; ++r) {                                               \
        pb0[r]     = (bf16_t)s[0][r];  pb0[4 + r] = (bf16_t)s[1][r];            \
        pb1[r]     = (bf16_t)s[2][r];  pb1[4 + r] = (bf16_t)s[3][r];            \
    }                                                                           \
    o0 = __builtin_amdgcn_mfma_f32_16x16x32_bf16(va_[0], pb0, o0, 0, 0, 0);     \
    o0 = __builtin_amdgcn_mfma_f32_16x16x32_bf16(va_[1], pb1, o0, 0, 0, 0);     \
    o1 = __builtin_amdgcn_mfma_f32_16x16x32_bf16(va_[2], pb0, o1, 0, 0, 0);     \
    o1 = __builtin_amdgcn_mfma_f32_16x16x32_bf16(va_[3], pb1, o1, 0, 0, 0);     \
} while (0)

    FA_LOAD(kha, kla, vaa, mka, 0);
    int kt = 0;
    for (; kt + 2 <= nkt; kt += 2) {
        FA_LOAD(khb, klb, vab, mkb, kt + 1);
        FA_COMPUTE(kha, kla, vaa, mka, kt);
        if (kt + 2 < nkt) FA_LOAD(kha, kla, vaa, mka, kt + 2);
        FA_COMPUTE(khb, klb, vab, mkb, kt + 1);
    }
    if (kt < nkt) FA_COMPUTE(kha, kla, vaa, mka, kt);

#undef FA_LOAD
#undef FA_COMPUTE

    // ---- epilogue: ctx hi/lo in A-frag layout ----
    // o0[r] = ctx[token][h*32 + 4lg + r]; o1[r] = ctx[token][h*32 + 16 + 4lg + r]
    // A-frag (K=256,K32=8): mb = token>>4 = b*64+qt*4+w; kb = h;
    //   lane = ((c%32)>>3)*16 + l15; j = (c%32)&7.
    const float inv = 1.0f / lsum;
    bf16x4 h0, l0, h1, l1;
#pragma unroll
    for (int r = 0; r < 4; ++r) {
        float f0 = o0[r] * inv;
        float f1 = o1[r] * inv;
        bf16_t hv0 = (bf16_t)f0;
        bf16_t hv1 = (bf16_t)f1;
        h0[r] = hv0;  l0[r] = (bf16_t)(f0 - (float)hv0);
        h1[r] = hv1;  l1[r] = (bf16_t)(f1 - (float)hv1);
    }
    const int mb = b * 64 + qt * 4 + w;
    const int lp0 = (lg >> 1) * 16 + l15;
    const int jb = 4 * (lg & 1);
    const size_t g0 = ((size_t)mb * 8 + h) * 64;
    const size_t i0 = (g0 + lp0) * 8 + jb;
    const size_t i1 = (g0 + lp0 + 32) * 8 + jb;
    *(bf16x4*)(Chi + i0) = h0;
    *(bf16x4*)(Chi + i1) = h1;
    *(bf16x4*)(Clo + i0) = l0;
    *(bf16x4*)(Clo + i1) = l1;
}

__global__ __launch_bounds__(256) void cast_kernel(
    const float* __restrict__ x, void* __restrict__ out, const int* __restrict__ flag)
{
    int f32 = *flag;
    int i = blockIdx.x * 256 + threadIdx.x;
    if (f32) ((float*)out)[i] = x[i];
    else ((bf16*)out)[i] = __float2bfloat16(x[i]);
}

// ---------------------------------------------------------------------------
extern "C" void kernel_launch(void* const* d_in, const int* in_sizes, int n_in,
                              void* d_out, int out_size, void* d_ws, size_t ws_size,
                              hipStream_t stream)
{
    const void* enc       = d_in[0];
    const void* dec       = d_in[1];
    const int*  enc_masks = (const int*)d_in[2];
    const int*  dec_masks = (const int*)d_in[3];
    const void* W_tgt = d_in[4];
    const void* b_tgt = d_in[5];
    const void* sa_Wq = d_in[6];
    const void* sa_bq = d_in[7];
    const void* sa_Wk = d_in[8];
    const void* sa_bk = d_in[9];
    const void* sa_Wv = d_in[10];
    const void* sa_bv = d_in[11];
    const void* sa_Wo = d_in[12];
    const void* sa_bo = d_in[13];
    const void* sa_ln_g = d_in[14];
    const void* sa_ln_b = d_in[15];
    const void* ca_Wq = d_in[16];
    const void* ca_bq = d_in[17];
    const void* ca_Wk = d_in[18];
    const void* ca_bk = d_in[19];
    const void* ca_Wv = d_in[20];
    const void* ca_bv = d_in[21];
    const void* ca_Wo = d_in[22];
    const void* ca_bo = d_in[23];
    const void* ca_ln_g = d_in[24];
    const void* ca_ln_b = d_in[25];
    const void* ff_W1 = d_in[26];
    const void* ff_b1 = d_in[27];
    const void* ff_W2 = d_in[28];
    const void* ff_b2 = d_in[29];
    const void* ff_ln_g = d_in[30];
    const void* ff_ln_b = d_in[31];

    const size_t M1 = (size_t)NTOK * D_;        // 1M floats
    float* ws = (float*)d_ws;
    float*  x      = ws;                                    // [0,1M) floats
    bf16_t* xhi    = (bf16_t*)(ws + 1 * M1);                // M1E elems (A-frag)
    bf16_t* xlo    = xhi + M1E;                             // [1M,2M)
    bf16_t* ctxhi  = (bf16_t*)(ws + 2 * M1);                // (A-frag)
    bf16_t* ctxlo  = ctxhi + M1E;                           // [2M,3M)
    bf16_t* enchi  = (bf16_t*)(ws + 3 * M1);                // (A-frag)
    bf16_t* enclo  = enchi + M1E;                           // [3M,4M)
    bf16_t* hhi    = (bf16_t*)(ws + 4 * M1);                // 4M elems [4M,6M) (A-frag)
    bf16_t* hlo    = (bf16_t*)(ws + 6 * M1);                // [6M,8M)
    bf16_t* qbuf   = (bf16_t*)(ws + 8 * M1);                // 2M elems [8M,9M)
    bf16_t* kbuf   = (bf16_t*)(ws + 9 * M1);                // [9M,10M)
    bf16_t* vtbuf  = (bf16_t*)(ws + 10 * M1);               // 1M elems [10M,10.5M)
    float*  pe     = ws + 10 * M1 + M1 / 2;                 // [10.5M,10.75M)
    int*    flag   = (int*)(ws + 10 * M1 + 3 * M1 / 4);
    bf16_t* Wf     = (bf16_t*)(ws + 11 * M1);               // 2*WTOT elems

    const int nElem = NTOK * D_;                // 1,048,576

    detect_kernel<<<1, 256, 0, stream>>>(enc, flag);
    prep_w_kernel<<<3072, 256, 0, stream>>>(
        sa_Wq, sa_Wk, sa_Wv, sa_Wo, ca_Wq, ca_Wk, ca_Wv, ca_Wo,
        ff_W1, ff_W2, Wf, flag);
    pe_build_kernel<<<(LD_ * D_) / 256, 256, 0, stream>>>(pe);
    embed_kernel<<<nElem / 256, 256, 0, stream>>>(dec, W_tgt, b_tgt, x, xhi, xlo, pe, flag);
    enc_split_kernel<<<nElem / 256, 256, 0, stream>>>(enc, enchi, enclo, flag);

    dim3 gProj(D_ / 64, NTOK / 32, 3);          // (4,128,3)
    dim3 gFF1(DFF_ / 64, NTOK / 32, 1);         // (16,128,1)
    dim3 gAttn(LD_ / 64, H_, B_);               // (16,8,4)

    for (int i = 0; i < NL_; ++i) {
        const size_t LB   = (size_t)i * 1048576;   // layer base in Wf (elements)
        const size_t bOff = (size_t)i * D_;

        // --- self attention ---
        gemmf_kernel<<<gProj, 256, 0, stream>>>(
            xhi, xlo, xhi, xlo, xhi, xlo,
            Wf, LB, 65536, sa_bq, sa_bk, sa_bv, bOff,
            qbuf, kbuf, vtbuf, nullptr, NTOK, D_, D_, 1, flag);
        fattn4_kernel<<<gAttn, 256, 0, stream>>>(qbuf, kbuf, vtbuf, ctxhi, ctxlo, dec_masks, 1);
        gemmln_kernel<<<NTOK / 16, 1024, 0, stream>>>(
            ctxhi, ctxlo, Wf, LB + 3 * 65536, sa_bo, x, xhi, xlo,
            sa_ln_g, sa_ln_b, bOff, D_, pe, 0, flag);

        // --- cross attention ---
        gemmf_kernel<<<gProj, 256, 0, stream>>>(
            xhi, xlo, enchi, enclo, enchi, enclo,
            Wf, LB + 4 * 65536, 65536, ca_bq, ca_bk, ca_bv, bOff,
            qbuf, kbuf, vtbuf, nullptr, NTOK, D_, D_, 1, flag);
        fattn4_kernel<<<gAttn, 256, 0, stream>>>(qbuf, kbuf, vtbuf, ctxhi, ctxlo, enc_masks, 0);
        gemmln_kernel<<<NTOK / 16, 1024, 0, stream>>>(
            ctxhi, ctxlo, Wf, LB + 7 * 65536, ca_bo, x, xhi, xlo,
            ca_ln_g, ca_ln_b, bOff, D_, pe, 0, flag);

        // --- FFN ---
        gemmf_kernel<<<gFF1, 256, 0, stream>>>(
            xhi, xlo, xhi, xlo, xhi, xlo,
            Wf, LB + 524288, 0, ff_b1, ff_b1, ff_b1, (size_t)i * DFF_,
            hhi, hhi, hhi, hlo, NTOK, DFF_, D_, 2, flag);
        gemmln_kernel<<<NTOK / 16, 1024, 0, stream>>>(
            hhi, hlo, Wf, LB + 786432, ff_b2, x, xhi, xlo,
            ff_ln_g, ff_ln_b, bOff, DFF_, pe, (i < NL_ - 1) ? 1 : 0, flag);
    }

    cast_kernel<<<nElem / 256, 256, 0, stream>>>(x, d_out, flag);
}

// Round 10
// 958.373 us; speedup vs baseline: 1.3914x; 1.0858x over previous
//
#include <hip/hip_runtime.h>
#include <hip/hip_bf16.h>

#define B_   4
#define LD_  1024
#define LE_  1024
#define D_   256
#define H_   8
#define DK_  32
#define DFF_ 1024
#define NL_  6
#define NTOK (B_ * LD_)   // 4096 decoder tokens; encoder also 4*1024 = 4096
#define M1E  1048576      // NTOK * D_ elements
#define WTOT 6291456      // total weight elements across 6 layers (frag layout)

typedef __hip_bfloat16 bf16;
typedef __bf16 bf16_t;
typedef bf16_t bf16x8 __attribute__((ext_vector_type(8)));
typedef bf16_t bf16x4 __attribute__((ext_vector_type(4)));
typedef float  f32x4  __attribute__((ext_vector_type(4)));

__device__ __forceinline__ float bits2f(unsigned short u) {
    union { unsigned int i; float f; } w; w.i = ((unsigned int)u) << 16; return w.f;
}
// dtype-flexible scalar load from tensor base + element index
__device__ __forceinline__ float ldx(const void* p, size_t i, int f32) {
    if (f32) return ((const float*)p)[i];
    return bits2f(((const unsigned short*)p)[i]);
}
// A-fragment index: element (m,k) of an [M][K] matrix, K32 = K/32.
// group = ((m>>4)*K32 + (k>>5))*64 + ((k>>3)&3)*16 + (m&15); elem j = k&7.
__device__ __forceinline__ size_t afrag_idx(int m, int k, int K32) {
    return ((((size_t)(m >> 4) * K32 + (k >> 5)) * 64
             + (size_t)(((k >> 3) & 3) * 16 + (m & 15))) << 3) + (k & 7);
}

// ---------------------------------------------------------------------------
// Detect input dtype (bf16 vs fp32). flag: 1=fp32, 0=bf16.
__global__ __launch_bounds__(256) void detect_kernel(
    const void* __restrict__ enc, int* __restrict__ flag)
{
    __shared__ int bad;
    if (threadIdx.x == 0) bad = 0;
    __syncthreads();
    const unsigned short* u = (const unsigned short*)enc;
    int b = 0;
    for (int i = threadIdx.x; i < 4096; i += 256) {
        unsigned short e = (u[i] >> 7) & 0xFF;
        if (e >= 142) b = 1;
    }
    if (b) atomicOr(&bad, 1);
    __syncthreads();
    if (threadIdx.x == 0) *flag = bad;
}

// ---------------------------------------------------------------------------
// Convert ALL weights to B-fragment-ready bf16 layout, once per launch.
// Per layer: t0..7 = sa_Wq,sa_Wk,sa_Wv,sa_Wo,ca_Wq,ca_Wk,ca_Wv,ca_Wo @ t*65536
// (256x256); W1 @ 524288 (256x1024); W2 @ 786432 (1024x256).
// group = (kb*(N/16)+nb)*64+lane; elem j: W[kb*32+8*(lane>>4)+j][nb*16+(lane&15)]
__global__ __launch_bounds__(256) void prep_w_kernel(
    const void* sWq, const void* sWk, const void* sWv, const void* sWo,
    const void* cWq, const void* cWk, const void* cWv, const void* cWo,
    const void* fW1, const void* fW2,
    bf16_t* __restrict__ Wf, const int* __restrict__ flag)
{
    const int f32 = *flag;
    const int g = blockIdx.x * 256 + threadIdx.x;   // 0..786431 frag-groups
    const int li = g >> 17;
    int r = g & 131071;
    const void* src;
    size_t so;
    int N;
    if (r < 65536) {
        int t = r >> 13; r &= 8191;
        N = 256; so = (size_t)li * 65536;
        if      (t == 0) src = sWq; else if (t == 1) src = sWk;
        else if (t == 2) src = sWv; else if (t == 3) src = sWo;
        else if (t == 4) src = cWq; else if (t == 5) src = cWk;
        else if (t == 6) src = cWv; else             src = cWo;
    } else if (r < 98304) {
        r -= 65536; N = 1024; so = (size_t)li * 262144; src = fW1;
    } else {
        r -= 98304; N = 256;  so = (size_t)li * 262144; src = fW2;
    }
    const int lane = r & 63;
    const int q2 = r >> 6;
    int nb, kb;
    if (N == 256) { nb = q2 & 15; kb = q2 >> 4; }
    else          { nb = q2 & 63; kb = q2 >> 6; }
    const int k = kb * 32 + 8 * (lane >> 4);
    const int n = nb * 16 + (lane & 15);
    const size_t out = (size_t)g * 8;
#pragma unroll
    for (int j = 0; j < 8; ++j) {
        float v = ldx(src, so + (size_t)(k + j) * N + n, f32);
        bf16_t hv = (bf16_t)v;
        Wf[out + j] = hv;
        if (f32) Wf[WTOT + out + j] = (bf16_t)(v - (float)hv);
    }
}

// ---------------------------------------------------------------------------
// build PE table [1024][256] once
__global__ __launch_bounds__(256) void pe_build_kernel(float* __restrict__ pe)
{
    int i = blockIdx.x * 256 + threadIdx.x;     // over LD_*D_ = 262144
    int d = i & (D_ - 1);
    int pos = i >> 8;
    int j = d & 127;
    float inv = powf(10000.0f, -2.0f * (float)j / (float)D_);
    float s = (float)pos * inv;
    pe[i] = (d < 128) ? sinf(s) : cosf(s);
}

// x = embed + PE; fp32 row-major + hi/lo bf16 in A-frag layout (K=256)
__global__ __launch_bounds__(256) void embed_kernel(
    const void* __restrict__ dec, const void* __restrict__ Wt,
    const void* __restrict__ bt, float* __restrict__ x,
    bf16_t* __restrict__ xhi, bf16_t* __restrict__ xlo,
    const float* __restrict__ pe, const int* __restrict__ flag)
{
    int f32 = *flag;
    int i = blockIdx.x * 256 + threadIdx.x;     // over NTOK * D_
    int d = i & (D_ - 1);
    int t = i >> 8;
    float a0 = ldx(dec, t * 3 + 0, f32);
    float a1 = ldx(dec, t * 3 + 1, f32);
    float a2 = ldx(dec, t * 3 + 2, f32);
    float v = ldx(bt, d, f32) + a0 * ldx(Wt, 0 * D_ + d, f32)
            + a1 * ldx(Wt, 1 * D_ + d, f32) + a2 * ldx(Wt, 2 * D_ + d, f32)
            + pe[i & (LD_ * D_ - 1)];
    x[i] = v;
    size_t fi = afrag_idx(t, d, 8);
    bf16_t hv = (bf16_t)v;
    xhi[fi] = hv;
    xlo[fi] = (bf16_t)(v - (float)hv);
}

// enc -> hi/lo bf16 in A-frag layout (K=256)
__global__ __launch_bounds__(256) void enc_split_kernel(
    const void* __restrict__ in, bf16_t* __restrict__ ehi, bf16_t* __restrict__ elo,
    const int* __restrict__ flag)
{
    int f32 = *flag;
    int i = blockIdx.x * 256 + threadIdx.x;
    int d = i & (D_ - 1);
    int t = i >> 8;
    float v = ldx(in, i, f32);
    size_t fi = afrag_idx(t, d, 8);
    bf16_t hv = (bf16_t)v;
    ehi[fi] = hv;
    elo[fi] = (bf16_t)(v - (float)hv);
}

// ---------------------------------------------------------------------------
// Fragment GEMM, depth-4 software-pipelined, dual accumulator chains.
// C = A @ W + bias. A hi/lo bf16 in A-FRAG layout; W = Wf frags (L2-hot).
// Zero LDS/barriers. BM=32, BN=64, 4 waves (2x2).
// mode 1: attention-prep epilogue (z0=Q,z1=K,z2=V fragment layouts)
__global__ __launch_bounds__(256) void gemmf_kernel(
    const bf16_t* __restrict__ Ah0, const bf16_t* __restrict__ Al0,
    const bf16_t* __restrict__ Ah1, const bf16_t* __restrict__ Al1,
    const bf16_t* __restrict__ Ah2, const bf16_t* __restrict__ Al2,
    const bf16_t* __restrict__ Wf, size_t wfBase, size_t wzStr,
    const void* __restrict__ b0, const void* __restrict__ b1,
    const void* __restrict__ b2, size_t bOff,
    bf16_t* __restrict__ C0, bf16_t* __restrict__ C1,
    bf16_t* __restrict__ C2,
    int M, int N, int K, const int* __restrict__ flag)
{
    const int f32 = *flag;
    const int z = blockIdx.z;
    const bf16_t* Ah = (z == 0) ? Ah0 : (z == 1) ? Ah1 : Ah2;
    const bf16_t* Al = (z == 0) ? Al0 : (z == 1) ? Al1 : Al2;
    const void* bias = (z == 0) ? b0 : (z == 1) ? b1 : b2;
    bf16_t* Cb = (z == 0) ? C0 : (z == 1) ? C1 : C2;

    const int tid = threadIdx.x;
    const int m0 = blockIdx.y * 32, n0 = blockIdx.x * 64;
    const int w = tid >> 6, l = tid & 63, l15 = l & 15, lg = l >> 4;
    const int wr = w >> 1, wc = w & 1;

    const bf16_t* wfp = Wf + wfBase + (size_t)z * wzStr;
    const int nbT = N >> 4;
    const int nb0 = (n0 >> 4) + 2 * wc;
    const int K32 = K >> 5;

    const int mb = (m0 >> 4) + wr;
    const bf16_t* ap  = Ah + ((size_t)mb * K32 * 64 + l) * 8;
    const bf16_t* alp = Al + ((size_t)mb * K32 * 64 + l) * 8;

    f32x4 acc0 = {0.f, 0.f, 0.f, 0.f};
    f32x4 acc1 = {0.f, 0.f, 0.f, 0.f};

    if (!f32) {
        f32x4 d0 = {0.f, 0.f, 0.f, 0.f};
        f32x4 d1 = {0.f, 0.f, 0.f, 0.f};
        bf16x8 A0, L0, P0, Q0, A1, L1, P1, Q1;
        bf16x8 A2, L2, P2, Q2, A3, L3, P3, Q3;
#define GF_LD(Ax, Lx, Px, Qx, KB) do {                                          \
        Ax = *(const bf16x8*)(ap + (size_t)(KB) * 512);                         \
        Lx = *(const bf16x8*)(alp + (size_t)(KB) * 512);                        \
        Px = *(const bf16x8*)(wfp + ((size_t)((KB) * nbT + nb0) * 64 + l) * 8); \
        Qx = *(const bf16x8*)(wfp + ((size_t)((KB) * nbT + nb0 + 1) * 64 + l) * 8); \
    } while (0)
#define GF_STEP(Ax, Lx, Px, Qx, KB) do {                                        \
        acc0 = __builtin_amdgcn_mfma_f32_16x16x32_bf16(Ax, Px, acc0, 0, 0, 0);  \
        acc1 = __builtin_amdgcn_mfma_f32_16x16x32_bf16(Ax, Qx, acc1, 0, 0, 0);  \
        d0   = __builtin_amdgcn_mfma_f32_16x16x32_bf16(Lx, Px, d0,   0, 0, 0);  \
        d1   = __builtin_amdgcn_mfma_f32_16x16x32_bf16(Lx, Qx, d1,   0, 0, 0);  \
        if ((KB) + 4 < K32) GF_LD(Ax, Lx, Px, Qx, (KB) + 4);                    \
    } while (0)
        GF_LD(A0, L0, P0, Q0, 0);
        GF_LD(A1, L1, P1, Q1, 1);
        GF_LD(A2, L2, P2, Q2, 2);
        GF_LD(A3, L3, P3, Q3, 3);
        for (int kb = 0; kb < K32; kb += 4) {
            GF_STEP(A0, L0, P0, Q0, kb);
            GF_STEP(A1, L1, P1, Q1, kb + 1);
            GF_STEP(A2, L2, P2, Q2, kb + 2);
            GF_STEP(A3, L3, P3, Q3, kb + 3);
        }
#undef GF_LD
#undef GF_STEP
#pragma unroll
        for (int r = 0; r < 4; ++r) { acc0[r] += d0[r]; acc1[r] += d1[r]; }
    } else {
        const bf16_t* wlp = wfp + WTOT;
        for (int kb = 0; kb < K32; ++kb) {
            bf16x8 ah  = *(const bf16x8*)(ap + (size_t)kb * 512);
            bf16x8 al8 = *(const bf16x8*)(alp + (size_t)kb * 512);
            bf16x8 bh0 = *(const bf16x8*)(wfp + ((size_t)(kb * nbT + nb0) * 64 + l) * 8);
            bf16x8 bh1 = *(const bf16x8*)(wfp + ((size_t)(kb * nbT + nb0 + 1) * 64 + l) * 8);
            bf16x8 bl0 = *(const bf16x8*)(wlp + ((size_t)(kb * nbT + nb0) * 64 + l) * 8);
            bf16x8 bl1 = *(const bf16x8*)(wlp + ((size_t)(kb * nbT + nb0 + 1) * 64 + l) * 8);
            acc0 = __builtin_amdgcn_mfma_f32_16x16x32_bf16(ah, bh0, acc0, 0, 0, 0);
            acc0 = __builtin_amdgcn_mfma_f32_16x16x32_bf16(al8, bh0, acc0, 0, 0, 0);
            acc0 = __builtin_amdgcn_mfma_f32_16x16x32_bf16(ah, bl0, acc0, 0, 0, 0);
            acc1 = __builtin_amdgcn_mfma_f32_16x16x32_bf16(ah, bh1, acc1, 0, 0, 0);
            acc1 = __builtin_amdgcn_mfma_f32_16x16x32_bf16(al8, bh1, acc1, 0, 0, 0);
            acc1 = __builtin_amdgcn_mfma_f32_16x16x32_bf16(ah, bl1, acc1, 0, 0, 0);
        }
    }

    // epilogue: C/D layout col=l15, row=4*lg+r; attention-prep layouts
    const int cm = m0 + 16 * wr + 4 * lg;
    const int cn = n0 + 32 * wc + l15;
    const float b0v = ldx(bias, bOff + cn, f32);
    const float b1v = ldx(bias, bOff + cn + 16, f32);
    const float qs = (z == 0) ? 0.17677669529663687f : 1.0f;   // 1/sqrt(32)
#pragma unroll
    for (int r = 0; r < 4; ++r) {
        const int token = cm + r;
#pragma unroll
        for (int cc = 0; cc < 2; ++cc) {
            const int d = cn + 16 * cc;
            const float v = ((cc == 0 ? acc0[r] : acc1[r]) + (cc == 0 ? b0v : b1v)) * qs;
            if (z < 2) {
                int bb = token >> 10, qw = (token >> 4) & 63, lt = token & 15;
                int hh = d >> 5, lg2 = (d >> 3) & 3, jj = d & 7;
                size_t base = ((size_t)((bb * 8 + hh) * 64 + qw)) * 1024
                            + (size_t)(lg2 * 16 + lt) * 8 + jj;
                bf16_t hv = (bf16_t)v;
                Cb[base]       = hv;
                Cb[base + 512] = (bf16_t)(v - (float)hv);
            } else {
                int bb = token >> 10, ktt = (token >> 6) & 15, c2 = (token >> 5) & 1;
                int w32 = token & 31;
                int lg2 = (w32 >> 2) & 3, jj = (w32 >> 4) * 4 + (w32 & 3);
                int hh = d >> 5, dvh = (d >> 4) & 1, lt = d & 15;
                size_t base = ((size_t)((bb * 8 + hh) * 16 + ktt)) * 2048
                            + c2 * 1024 + dvh * 512 + (size_t)(lg2 * 16 + lt) * 8 + jj;
                Cb[base] = (bf16_t)v;
            }
        }
    }
}

// ---------------------------------------------------------------------------
// Hoisted cross-attn K/V projections for ALL layers (enc-only dependence).
// grid (4, 128, 12): z -> layer L=z>>1, which=z&1 (0=K frag, 1=V frag).
// Same math/epilogue as gemmf z=1/z=2.
__global__ __launch_bounds__(256) void gemmkv_kernel(
    const bf16_t* __restrict__ Ah, const bf16_t* __restrict__ Al,
    const bf16_t* __restrict__ Wf,
    const void* __restrict__ bk, const void* __restrict__ bv,
    bf16_t* __restrict__ kvK, bf16_t* __restrict__ kvV,
    const int* __restrict__ flag)
{
    const int f32 = *flag;
    const int L = blockIdx.z >> 1, which = blockIdx.z & 1;
    const void* bias = which ? bv : bk;
    const size_t bOff = (size_t)L * 256;
    bf16_t* Cb = which ? (kvV + (size_t)L * M1E) : (kvK + (size_t)L * 2 * M1E);

    const int tid = threadIdx.x;
    const int m0 = blockIdx.y * 32, n0 = blockIdx.x * 64;
    const int w = tid >> 6, l = tid & 63, l15 = l & 15, lg = l >> 4;
    const int wr = w >> 1, wc = w & 1;

    const bf16_t* wfp = Wf + (size_t)L * 1048576 + (size_t)(5 + which) * 65536;
    const int nb0 = (n0 >> 4) + 2 * wc;

    const int mb = (m0 >> 4) + wr;
    const bf16_t* ap  = Ah + ((size_t)mb * 8 * 64 + l) * 8;
    const bf16_t* alp = Al + ((size_t)mb * 8 * 64 + l) * 8;

    f32x4 acc0 = {0.f, 0.f, 0.f, 0.f};
    f32x4 acc1 = {0.f, 0.f, 0.f, 0.f};
    f32x4 d0 = {0.f, 0.f, 0.f, 0.f};
    f32x4 d1 = {0.f, 0.f, 0.f, 0.f};

    for (int kb = 0; kb < 8; ++kb) {
        bf16x8 ah  = *(const bf16x8*)(ap + (size_t)kb * 512);
        bf16x8 al8 = *(const bf16x8*)(alp + (size_t)kb * 512);
        bf16x8 bh0 = *(const bf16x8*)(wfp + ((size_t)(kb * 16 + nb0) * 64 + l) * 8);
        bf16x8 bh1 = *(const bf16x8*)(wfp + ((size_t)(kb * 16 + nb0 + 1) * 64 + l) * 8);
        acc0 = __builtin_amdgcn_mfma_f32_16x16x32_bf16(ah, bh0, acc0, 0, 0, 0);
        acc1 = __builtin_amdgcn_mfma_f32_16x16x32_bf16(ah, bh1, acc1, 0, 0, 0);
        d0   = __builtin_amdgcn_mfma_f32_16x16x32_bf16(al8, bh0, d0, 0, 0, 0);
        d1   = __builtin_amdgcn_mfma_f32_16x16x32_bf16(al8, bh1, d1, 0, 0, 0);
        if (f32) {
            const bf16_t* wlp = wfp + WTOT;
            bf16x8 bl0 = *(const bf16x8*)(wlp + ((size_t)(kb * 16 + nb0) * 64 + l) * 8);
            bf16x8 bl1 = *(const bf16x8*)(wlp + ((size_t)(kb * 16 + nb0 + 1) * 64 + l) * 8);
            acc0 = __builtin_amdgcn_mfma_f32_16x16x32_bf16(ah, bl0, acc0, 0, 0, 0);
            acc1 = __builtin_amdgcn_mfma_f32_16x16x32_bf16(ah, bl1, acc1, 0, 0, 0);
        }
    }
#pragma unroll
    for (int r = 0; r < 4; ++r) { acc0[r] += d0[r]; acc1[r] += d1[r]; }

    const int cm = m0 + 16 * wr + 4 * lg;
    const int cn = n0 + 32 * wc + l15;
    const float b0v = ldx(bias, bOff + cn, f32);
    const float b1v = ldx(bias, bOff + cn + 16, f32);
#pragma unroll
    for (int r = 0; r < 4; ++r) {
        const int token = cm + r;
#pragma unroll
        for (int cc = 0; cc < 2; ++cc) {
            const int d = cn + 16 * cc;
            const float v = (cc == 0 ? acc0[r] : acc1[r]) + (cc == 0 ? b0v : b1v);
            if (which == 0) {      // K frag (hi/lo)
                int bb = token >> 10, qw = (token >> 4) & 63, lt = token & 15;
                int hh = d >> 5, lg2 = (d >> 3) & 3, jj = d & 7;
                size_t base = ((size_t)((bb * 8 + hh) * 64 + qw)) * 1024
                            + (size_t)(lg2 * 16 + lt) * 8 + jj;
                bf16_t hv = (bf16_t)v;
                Cb[base]       = hv;
                Cb[base + 512] = (bf16_t)(v - (float)hv);
            } else {               // V sigma frag
                int bb = token >> 10, ktt = (token >> 6) & 15, c2 = (token >> 5) & 1;
                int w32 = token & 31;
                int lg2 = (w32 >> 2) & 3, jj = (w32 >> 4) * 4 + (w32 & 3);
                int hh = d >> 5, dvh = (d >> 4) & 1, lt = d & 15;
                size_t base = ((size_t)((bb * 8 + hh) * 16 + ktt)) * 2048
                            + c2 * 1024 + dvh * 512 + (size_t)(lg2 * 16 + lt) * 8 + jj;
                Cb[base] = (bf16_t)v;
            }
        }
    }
}

// ---------------------------------------------------------------------------
// Fragment GEMM + residual + LayerNorm, depth-4 pipelined, dual chains.
// x = LN(A@W + bias + x)*g + b [+pe]; emits x hi/lo in A-frag layout.
// BM=16, N=256, 1024 thr = 16 waves (wave w owns cols 16w..16w+15).
__global__ __launch_bounds__(1024) void gemmln_kernel(
    const bf16_t* __restrict__ Ah, const bf16_t* __restrict__ Al,
    const bf16_t* __restrict__ Wf, size_t wfBase,
    const void* __restrict__ bias, float* __restrict__ x,
    bf16_t* __restrict__ xhi, bf16_t* __restrict__ xlo,
    const void* __restrict__ g, const void* __restrict__ bt,
    size_t bOff, int K,
    const float* __restrict__ pe, int addpe, const int* __restrict__ flag)
{
    const int f32 = *flag;
    __shared__ float red1[16][16];
    __shared__ float red2[16][16];
    __shared__ float mrow[16], irow[16];

    const int tid = threadIdx.x;
    const int m0 = blockIdx.x * 16;
    const int w = tid >> 6, l = tid & 63, l15 = l & 15, lg = l >> 4;
    const int K32 = K >> 5;

    const bf16_t* ap  = Ah + ((size_t)blockIdx.x * K32 * 64 + l) * 8;
    const bf16_t* alp = Al + ((size_t)blockIdx.x * K32 * 64 + l) * 8;
    const bf16_t* wfp = Wf + wfBase;

    f32x4 acc = {0.f, 0.f, 0.f, 0.f};

    if (!f32) {
        f32x4 accB = {0.f, 0.f, 0.f, 0.f};
        bf16x8 A0, L0, B0, A1, L1, B1, A2, L2, B2, A3, L3, B3;
#define GL_LD(Ax, Lx, Bx, KB) do {                                              \
        Ax = *(const bf16x8*)(ap + (size_t)(KB) * 512);                         \
        Lx = *(const bf16x8*)(alp + (size_t)(KB) * 512);                        \
        Bx = *(const bf16x8*)(wfp + ((size_t)((KB) * 16 + w) * 64 + l) * 8);    \
    } while (0)
#define GL_STEP(Ax, Lx, Bx, KB) do {                                            \
        acc  = __builtin_amdgcn_mfma_f32_16x16x32_bf16(Ax, Bx, acc,  0, 0, 0);  \
        accB = __builtin_amdgcn_mfma_f32_16x16x32_bf16(Lx, Bx, accB, 0, 0, 0);  \
        if ((KB) + 4 < K32) GL_LD(Ax, Lx, Bx, (KB) + 4);                        \
    } while (0)
        GL_LD(A0, L0, B0, 0);
        GL_LD(A1, L1, B1, 1);
        GL_LD(A2, L2, B2, 2);
        GL_LD(A3, L3, B3, 3);
        for (int kb = 0; kb < K32; kb += 4) {
            GL_STEP(A0, L0, B0, kb);
            GL_STEP(A1, L1, B1, kb + 1);
            GL_STEP(A2, L2, B2, kb + 2);
            GL_STEP(A3, L3, B3, kb + 3);
        }
#undef GL_LD
#undef GL_STEP
#pragma unroll
        for (int r = 0; r < 4; ++r) acc[r] += accB[r];
    } else {
        const bf16_t* wlp = wfp + WTOT;
        for (int kb = 0; kb < K32; ++kb) {
            bf16x8 ah  = *(const bf16x8*)(ap + (size_t)kb * 512);
            bf16x8 al8 = *(const bf16x8*)(alp + (size_t)kb * 512);
            bf16x8 bh  = *(const bf16x8*)(wfp + ((size_t)(kb * 16 + w) * 64 + l) * 8);
            bf16x8 bl  = *(const bf16x8*)(wlp + ((size_t)(kb * 16 + w) * 64 + l) * 8);
            acc = __builtin_amdgcn_mfma_f32_16x16x32_bf16(ah, bh, acc, 0, 0, 0);
            acc = __builtin_amdgcn_mfma_f32_16x16x32_bf16(al8, bh, acc, 0, 0, 0);
            acc = __builtin_amdgcn_mfma_f32_16x16x32_bf16(ah, bl, acc, 0, 0, 0);
        }
    }

    // ---- v = acc + bias + residual; LN stats (rows 4*lg+r, col c) ----
    const int c = 16 * w + l15;
    const float bv = ldx(bias, bOff + c, f32);
    f32x4 v;
    float s1[4], s2[4];
#pragma unroll
    for (int r = 0; r < 4; ++r) {
        int tok = m0 + 4 * lg + r;
        v[r] = acc[r] + bv + x[(size_t)tok * 256 + c];
        s1[r] = v[r];
        s2[r] = v[r] * v[r];
    }
#pragma unroll
    for (int r = 0; r < 4; ++r) {
        s1[r] += __shfl_xor(s1[r], 1);  s2[r] += __shfl_xor(s2[r], 1);
        s1[r] += __shfl_xor(s1[r], 2);  s2[r] += __shfl_xor(s2[r], 2);
        s1[r] += __shfl_xor(s1[r], 4);  s2[r] += __shfl_xor(s2[r], 4);
        s1[r] += __shfl_xor(s1[r], 8);  s2[r] += __shfl_xor(s2[r], 8);
    }
    if (l15 == 0) {
#pragma unroll
        for (int r = 0; r < 4; ++r) {
            red1[w][4 * lg + r] = s1[r];
            red2[w][4 * lg + r] = s2[r];
        }
    }
    __syncthreads();
    if (tid < 16) {
        float t1 = 0.f, t2 = 0.f;
#pragma unroll
        for (int ww = 0; ww < 16; ++ww) { t1 += red1[ww][tid]; t2 += red2[ww][tid]; }
        float mean = t1 * (1.0f / 256.0f);
        float var  = t2 * (1.0f / 256.0f) - mean * mean;
        mrow[tid] = mean;
        irow[tid] = 1.0f / sqrtf(var + 1e-5f);
    }
    __syncthreads();

    const float gv  = ldx(g,  bOff + c, f32);
    const float btv = ldx(bt, bOff + c, f32);
#pragma unroll
    for (int r = 0; r < 4; ++r) {
        int row = 4 * lg + r;
        int tok = m0 + row;
        float out = (v[r] - mrow[row]) * irow[row] * gv + btv;
        if (addpe) out += pe[(size_t)(tok & (LD_ - 1)) * 256 + c];
        x[(size_t)tok * 256 + c] = out;
        size_t fi = afrag_idx(tok, c, 8);
        bf16_t hv = (bf16_t)out;
        xhi[fi] = hv;
        xlo[fi] = (bf16_t)(out - (float)hv);
    }
}

// ---------------------------------------------------------------------------
// Fused FFN: x = LN(relu(x@W1+b1)@W2 + b2 + x)*g + b [+pe] [-> d_out].
// BM=16, 1024 thr = 16 waves. Stage1: wave w computes h cols 64w..64w+63
// (4 frags, dual chains). h staged in LDS as FF2 A-fragments (hi/lo bf16,
// bit-identical split). Stage2: FF2 K32=32 from LDS, dual chains, + LN.
__global__ __launch_bounds__(1024) void ffn_kernel(
    const bf16_t* __restrict__ Ah, const bf16_t* __restrict__ Al,
    const bf16_t* __restrict__ Wf, size_t w1Base, size_t w2Base,
    const void* __restrict__ b1, const void* __restrict__ b2,
    size_t b1Off, size_t b2Off, float* __restrict__ x,
    bf16_t* __restrict__ xhi, bf16_t* __restrict__ xlo,
    const void* __restrict__ g, const void* __restrict__ bt,
    const float* __restrict__ pe, int addpe,
    void* __restrict__ finalOut, int writeFinal,
    const int* __restrict__ flag)
{
    const int f32 = *flag;
    __shared__ __align__(16) bf16_t Hhi[32][512];   // [kb][lane*8+j]
    __shared__ __align__(16) bf16_t Hlo[32][512];
    __shared__ float red1[16][16];
    __shared__ float red2[16][16];
    __shared__ float mrow[16], irow[16];

    const int tid = threadIdx.x;
    const int m0 = blockIdx.x * 16;
    const int w = tid >> 6, l = tid & 63, l15 = l & 15, lg = l >> 4;

    const bf16_t* ap  = Ah + ((size_t)blockIdx.x * 8 * 64 + l) * 8;
    const bf16_t* alp = Al + ((size_t)blockIdx.x * 8 * 64 + l) * 8;
    const bf16_t* wfp1 = Wf + w1Base;

    // ---- stage 1: h[16][64w..64w+63] = relu(x@W1+b1) ----
    f32x4 a1c[4] = {{0,0,0,0},{0,0,0,0},{0,0,0,0},{0,0,0,0}};
    f32x4 a1d[4] = {{0,0,0,0},{0,0,0,0},{0,0,0,0},{0,0,0,0}};
    if (!f32) {
        for (int kb = 0; kb < 8; ++kb) {
            bf16x8 A = *(const bf16x8*)(ap + (size_t)kb * 512);
            bf16x8 L = *(const bf16x8*)(alp + (size_t)kb * 512);
#pragma unroll
            for (int c = 0; c < 4; ++c) {
                bf16x8 Bc = *(const bf16x8*)(wfp1 + ((size_t)(kb * 64 + 4 * w + c) * 64 + l) * 8);
                a1c[c] = __builtin_amdgcn_mfma_f32_16x16x32_bf16(A, Bc, a1c[c], 0, 0, 0);
                a1d[c] = __builtin_amdgcn_mfma_f32_16x16x32_bf16(L, Bc, a1d[c], 0, 0, 0);
            }
        }
#pragma unroll
        for (int c = 0; c < 4; ++c)
#pragma unroll
            for (int r = 0; r < 4; ++r) a1c[c][r] += a1d[c][r];
    } else {
        const bf16_t* wlp1 = wfp1 + WTOT;
        for (int kb = 0; kb < 8; ++kb) {
            bf16x8 A = *(const bf16x8*)(ap + (size_t)kb * 512);
            bf16x8 L = *(const bf16x8*)(alp + (size_t)kb * 512);
#pragma unroll
            for (int c = 0; c < 4; ++c) {
                bf16x8 Bc = *(const bf16x8*)(wfp1 + ((size_t)(kb * 64 + 4 * w + c) * 64 + l) * 8);
                bf16x8 Blc = *(const bf16x8*)(wlp1 + ((size_t)(kb * 64 + 4 * w + c) * 64 + l) * 8);
                a1c[c] = __builtin_amdgcn_mfma_f32_16x16x32_bf16(A, Bc, a1c[c], 0, 0, 0);
                a1c[c] = __builtin_amdgcn_mfma_f32_16x16x32_bf16(L, Bc, a1c[c], 0, 0, 0);
                a1c[c] = __builtin_amdgcn_mfma_f32_16x16x32_bf16(A, Blc, a1c[c], 0, 0, 0);
            }
        }
    }
    // relu + bias + bf16 hi/lo split -> LDS in FF2 A-frag order
#pragma unroll
    for (int c = 0; c < 4; ++c) {
        const int col = 64 * w + 16 * c + l15;
        const float bv = ldx(b1, b1Off + col, f32);
        const int kb = col >> 5;
        const int kgrp = (col >> 3) & 3;
        const int jj = col & 7;
#pragma unroll
        for (int r = 0; r < 4; ++r) {
            float v = fmaxf(a1c[c][r] + bv, 0.0f);
            int lane2 = kgrp * 16 + 4 * lg + r;
            bf16_t hv = (bf16_t)v;
            Hhi[kb][lane2 * 8 + jj] = hv;
            Hlo[kb][lane2 * 8 + jj] = (bf16_t)(v - (float)hv);
        }
    }
    __syncthreads();

    // ---- stage 2: t = h@W2 + b2; wave w owns out cols 16w..16w+15 ----
    const bf16_t* wfp2 = Wf + w2Base;
    f32x4 acc = {0.f, 0.f, 0.f, 0.f};
    if (!f32) {
        f32x4 accB = {0.f, 0.f, 0.f, 0.f};
#pragma unroll 4
        for (int kb = 0; kb < 32; ++kb) {
            bf16x8 A2 = *(const bf16x8*)&Hhi[kb][l * 8];
            bf16x8 L2 = *(const bf16x8*)&Hlo[kb][l * 8];
            bf16x8 B2 = *(const bf16x8*)(wfp2 + ((size_t)(kb * 16 + w) * 64 + l) * 8);
            acc  = __builtin_amdgcn_mfma_f32_16x16x32_bf16(A2, B2, acc,  0, 0, 0);
            accB = __builtin_amdgcn_mfma_f32_16x16x32_bf16(L2, B2, accB, 0, 0, 0);
        }
#pragma unroll
        for (int r = 0; r < 4; ++r) acc[r] += accB[r];
    } else {
        const bf16_t* wlp2 = wfp2 + WTOT;
        for (int kb = 0; kb < 32; ++kb) {
            bf16x8 A2 = *(const bf16x8*)&Hhi[kb][l * 8];
            bf16x8 L2 = *(const bf16x8*)&Hlo[kb][l * 8];
            bf16x8 B2 = *(const bf16x8*)(wfp2 + ((size_t)(kb * 16 + w) * 64 + l) * 8);
            bf16x8 Bl2 = *(const bf16x8*)(wlp2 + ((size_t)(kb * 16 + w) * 64 + l) * 8);
            acc = __builtin_amdgcn_mfma_f32_16x16x32_bf16(A2, B2, acc, 0, 0, 0);
            acc = __builtin_amdgcn_mfma_f32_16x16x32_bf16(L2, B2, acc, 0, 0, 0);
            acc = __builtin_amdgcn_mfma_f32_16x16x32_bf16(A2, Bl2, acc, 0, 0, 0);
        }
    }

    // ---- residual + LN (identical structure to gemmln) ----
    const int c = 16 * w + l15;
    const float bv2 = ldx(b2, b2Off + c, f32);
    f32x4 v;
    float s1[4], s2[4];
#pragma unroll
    for (int r = 0; r < 4; ++r) {
        int tok = m0 + 4 * lg + r;
        v[r] = acc[r] + bv2 + x[(size_t)tok * 256 + c];
        s1[r] = v[r];
        s2[r] = v[r] * v[r];
    }
#pragma unroll
    for (int r = 0; r < 4; ++r) {
        s1[r] += __shfl_xor(s1[r], 1);  s2[r] += __shfl_xor(s2[r], 1);
        s1[r] += __shfl_xor(s1[r], 2);  s2[r] += __shfl_xor(s2[r], 2);
        s1[r] += __shfl_xor(s1[r], 4);  s2[r] += __shfl_xor(s2[r], 4);
        s1[r] += __shfl_xor(s1[r], 8);  s2[r] += __shfl_xor(s2[r], 8);
    }
    if (l15 == 0) {
#pragma unroll
        for (int r = 0; r < 4; ++r) {
            red1[w][4 * lg + r] = s1[r];
            red2[w][4 * lg + r] = s2[r];
        }
    }
    __syncthreads();
    if (tid < 16) {
        float t1 = 0.f, t2 = 0.f;
#pragma unroll
        for (int ww = 0; ww < 16; ++ww) { t1 += red1[ww][tid]; t2 += red2[ww][tid]; }
        float mean = t1 * (1.0f / 256.0f);
        float var  = t2 * (1.0f / 256.0f) - mean * mean;
        mrow[tid] = mean;
        irow[tid] = 1.0f / sqrtf(var + 1e-5f);
    }
    __syncthreads();

    const float gv  = ldx(g,  b2Off + c, f32);
    const float btv = ldx(bt, b2Off + c, f32);
#pragma unroll
    for (int r = 0; r < 4; ++r) {
        int row = 4 * lg + r;
        int tok = m0 + row;
        float out = (v[r] - mrow[row]) * irow[row] * gv + btv;
        if (addpe) out += pe[(size_t)(tok & (LD_ - 1)) * 256 + c];
        size_t idx = (size_t)tok * 256 + c;
        x[idx] = out;
        size_t fi = afrag_idx(tok, c, 8);
        bf16_t hv = (bf16_t)out;
        xhi[fi] = hv;
        xlo[fi] = (bf16_t)(out - (float)hv);
        if (writeFinal) {
            if (f32) ((float*)finalOut)[idx] = out;
            else ((bf16*)finalOut)[idx] = __float2bfloat16(out);
        }
    }
}

// ---------------------------------------------------------------------------
// Swapped-operand MFMA flash attention, fragment-ready operands, register
// double-buffered, zero LDS/barriers. Emits ctx hi/lo in A-FRAG layout.
__global__ __launch_bounds__(256) void fattn4_kernel(
    const bf16_t* __restrict__ Qf, const bf16_t* __restrict__ Kf,
    const bf16_t* __restrict__ Vf,
    bf16_t* __restrict__ Chi, bf16_t* __restrict__ Clo,
    const int* __restrict__ mask, int causal)
{
    const int tid = threadIdx.x;
    const int qt = (int)blockIdx.x ^ ((((int)blockIdx.z >> 1) & 1) << 3);
    const int h = blockIdx.y, b = blockIdx.z;
    const int w = tid >> 6, l = tid & 63, l15 = l & 15, lg = l >> 4;
    const int bh = b * H_ + h;

    const size_t qbase = ((size_t)(bh * 64 + qt * 4 + w)) * 1024 + l * 8;
    const bf16x8 qh = *(const bf16x8*)(Qf + qbase);
    const bf16x8 ql = *(const bf16x8*)(Qf + qbase + 512);
    const int q_global = qt * 64 + w * 16 + l15;

    const bf16_t* kp = Kf + (size_t)bh * 64 * 1024 + l * 8;
    const bf16_t* vp = Vf + (size_t)bh * 16 * 2048 + l * 8;
    const int*    mp = mask + b * 1024 + 4 * lg;

    float m = -3.0e38f, lsum = 0.0f;
    f32x4 o0 = {0.f, 0.f, 0.f, 0.f};
    f32x4 o1 = {0.f, 0.f, 0.f, 0.f};

    const int nkt = causal ? (qt + 1) : (LE_ / 64);

    bf16x8 kha[4], kla[4], vaa[4];  int4 mka[4];
    bf16x8 khb[4], klb[4], vab[4];  int4 mkb[4];

#define FA_LOAD(kh_, kl_, va_, mk_, KT) do {                                    \
    _Pragma("unroll")                                                           \
    for (int nt = 0; nt < 4; ++nt) {                                            \
        kh_[nt] = *(const bf16x8*)(kp + (size_t)(KT) * 4096 + nt * 1024);       \
        kl_[nt] = *(const bf16x8*)(kp + (size_t)(KT) * 4096 + nt * 1024 + 512); \
    }                                                                           \
    va_[0] = *(const bf16x8*)(vp + (size_t)(KT) * 2048);                        \
    va_[1] = *(const bf16x8*)(vp + (size_t)(KT) * 2048 + 1024);                 \
    va_[2] = *(const bf16x8*)(vp + (size_t)(KT) * 2048 + 512);                  \
    va_[3] = *(const bf16x8*)(vp + (size_t)(KT) * 2048 + 1536);                 \
    _Pragma("unroll")                                                           \
    for (int nt = 0; nt < 4; ++nt)                                              \
        mk_[nt] = *(const int4*)(mp + (KT) * 64 + nt * 16);                     \
} while (0)

#define FA_COMPUTE(kh_, kl_, va_, mk_, KT) do {                                 \
    f32x4 s[4];                                                                 \
    _Pragma("unroll")                                                           \
    for (int nt = 0; nt < 4; ++nt) {                                            \
        f32x4 acc = {0.f, 0.f, 0.f, 0.f};                                       \
        acc = __builtin_amdgcn_mfma_f32_16x16x32_bf16(kh_[nt], qh, acc, 0,0,0); \
        acc = __builtin_amdgcn_mfma_f32_16x16x32_bf16(kl_[nt], qh, acc, 0,0,0); \
        acc = __builtin_amdgcn_mfma_f32_16x16x32_bf16(kh_[nt], ql, acc, 0,0,0); \
        s[nt] = acc;                                                            \
    }                                                                           \
    float pm = -3.0e38f;                                                        \
    _Pragma("unroll")                                                           \
    for (int nt = 0; nt < 4; ++nt) {                                            \
        _Pragma("unroll")                                                       \
        for (int r = 0; r < 4; ++r) {                                           \
            int key = (KT) * 64 + 16 * nt + 4 * lg + r;                         \
            int mv = (r==0)?mk_[nt].x:(r==1)?mk_[nt].y:(r==2)?mk_[nt].z:mk_[nt].w; \
            bool dead = (mv != 0) || (causal && key > q_global);                \
            float v = dead ? -1e30f : s[nt][r];                                 \
            s[nt][r] = v;                                                       \
            pm = fmaxf(pm, v);                                                  \
        }                                                                       \
    }                                                                           \
    pm = fmaxf(pm, __shfl_xor(pm, 16));                                         \
    pm = fmaxf(pm, __shfl_xor(pm, 32));                                         \
    float mnew = fmaxf(m, pm);                                                  \
    float alpha = __expf(m - mnew);                                             \
    m = mnew;                                                                   \
    float psum = 0.f;                                                           \
    _Pragma("unroll")                                                           \
    for (int nt = 0; nt < 4; ++nt) {                                            \
        _Pragma("unroll")                                                       \
        for (int r = 0; r < 4; ++r) {                                           \
            float p = __expf(s[nt][r] - m);                                     \
            s[nt][r] = p;                                                       \
            psum += p;                                                          \
        }                                                                       \
    }                                                                           \
    psum += __shfl_xor(psum, 16);                                               \
    psum += __shfl_xor(psum, 32);                                               \
    lsum = lsum * alpha + psum;                                                 \
    _Pragma("unroll")                                                           \
    for (int r = 0; r < 4; ++r) { o0[r] *= alpha; o1[r] *= alpha; }             \
    bf16x8 pb0, pb1;                                                            \
    _Pragma("unroll")                                                           \
    for (int r = 0; r < 4; ++r) {                                               \
        pb0[r]     = (bf16_t)s[0][r];  pb0[4 + r] = (bf16_t)s[1][r];            \
        pb1[r]     = (bf16_t)s[2][r];  pb1[4 + r] = (bf16_t)s[3][r];            \
    }                                                                           \
    o0 = __builtin_amdgcn_mfma_f32_16x16x32_bf16(va_[0], pb0, o0, 0, 0, 0);     \
    o0 = __builtin_amdgcn_mfma_f32_16x16x32_bf16(va_[1], pb1, o0, 0, 0, 0);     \
    o1 = __builtin_amdgcn_mfma_f32_16x16x32_bf16(va_[2], pb0, o1, 0, 0, 0);     \
    o1 = __builtin_amdgcn_mfma_f32_16x16x32_bf16(va_[3], pb1, o1, 0, 0, 0);     \
} while (0)

    FA_LOAD(kha, kla, vaa, mka, 0);
    int kt = 0;
    for (; kt + 2 <= nkt; kt += 2) {
        FA_LOAD(khb, klb, vab, mkb, kt + 1);
        FA_COMPUTE(kha, kla, vaa, mka, kt);
        if (kt + 2 < nkt) FA_LOAD(kha, kla, vaa, mka, kt + 2);
        FA_COMPUTE(khb, klb, vab, mkb, kt + 1);
    }
    if (kt < nkt) FA_COMPUTE(kha, kla, vaa, mka, kt);

#undef FA_LOAD
#undef FA_COMPUTE

    // ---- epilogue: ctx hi/lo in A-frag layout ----
    const float inv = 1.0f / lsum;
    bf16x4 h0, l0, h1, l1;
#pragma unroll
    for (int r = 0; r < 4; ++r) {
        float f0 = o0[r] * inv;
        float f1 = o1[r] * inv;
        bf16_t hv0 = (bf16_t)f0;
        bf16_t hv1 = (bf16_t)f1;
        h0[r] = hv0;  l0[r] = (bf16_t)(f0 - (float)hv0);
        h1[r] = hv1;  l1[r] = (bf16_t)(f1 - (float)hv1);
    }
    const int mb = b * 64 + qt * 4 + w;
    const int lp0 = (lg >> 1) * 16 + l15;
    const int jb = 4 * (lg & 1);
    const size_t g0 = ((size_t)mb * 8 + h) * 64;
    const size_t i0 = (g0 + lp0) * 8 + jb;
    const size_t i1 = (g0 + lp0 + 32) * 8 + jb;
    *(bf16x4*)(Chi + i0) = h0;
    *(bf16x4*)(Chi + i1) = h1;
    *(bf16x4*)(Clo + i0) = l0;
    *(bf16x4*)(Clo + i1) = l1;
}

// ---------------------------------------------------------------------------
extern "C" void kernel_launch(void* const* d_in, const int* in_sizes, int n_in,
                              void* d_out, int out_size, void* d_ws, size_t ws_size,
                              hipStream_t stream)
{
    const void* enc       = d_in[0];
    const void* dec       = d_in[1];
    const int*  enc_masks = (const int*)d_in[2];
    const int*  dec_masks = (const int*)d_in[3];
    const void* W_tgt = d_in[4];
    const void* b_tgt = d_in[5];
    const void* sa_Wq = d_in[6];
    const void* sa_bq = d_in[7];
    const void* sa_Wk = d_in[8];
    const void* sa_bk = d_in[9];
    const void* sa_Wv = d_in[10];
    const void* sa_bv = d_in[11];
    const void* sa_Wo = d_in[12];
    const void* sa_bo = d_in[13];
    const void* sa_ln_g = d_in[14];
    const void* sa_ln_b = d_in[15];
    const void* ca_Wq = d_in[16];
    const void* ca_bq = d_in[17];
    const void* ca_Wk = d_in[18];
    const void* ca_bk = d_in[19];
    const void* ca_Wv = d_in[20];
    const void* ca_bv = d_in[21];
    const void* ca_Wo = d_in[22];
    const void* ca_bo = d_in[23];
    const void* ca_ln_g = d_in[24];
    const void* ca_ln_b = d_in[25];
    const void* ff_W1 = d_in[26];
    const void* ff_b1 = d_in[27];
    const void* ff_W2 = d_in[28];
    const void* ff_b2 = d_in[29];
    const void* ff_ln_g = d_in[30];
    const void* ff_ln_b = d_in[31];

    const size_t M1 = (size_t)NTOK * D_;        // 1M floats (4 MB units)
    float* ws = (float*)d_ws;
    float*  x      = ws;                                    // [0,1)
    bf16_t* xhi    = (bf16_t*)(ws + 1 * M1);                // [1,2)
    bf16_t* xlo    = xhi + M1E;
    bf16_t* ctxhi  = (bf16_t*)(ws + 2 * M1);                // [2,3)
    bf16_t* ctxlo  = ctxhi + M1E;
    bf16_t* enchi  = (bf16_t*)(ws + 3 * M1);                // [3,4)
    bf16_t* enclo  = enchi + M1E;
    bf16_t* qbuf   = (bf16_t*)(ws + 4 * M1);                // [4,5)
    bf16_t* kbuf   = (bf16_t*)(ws + 5 * M1);                // [5,6)
    bf16_t* vtbuf  = (bf16_t*)(ws + 6 * M1);                // [6,6.5)
    float*  pe     = ws + 6 * M1 + M1 / 2;                  // [6.5,6.75)
    int*    flag   = (int*)(ws + 6 * M1 + 3 * M1 / 4);
    bf16_t* Wf     = (bf16_t*)(ws + 7 * M1);                // 2*WTOT el = [7,13.3)
    bf16_t* kvK    = (bf16_t*)(ws + 14 * M1);               // 6 x 2*M1E el = [14,20)
    bf16_t* kvV    = (bf16_t*)(ws + 20 * M1);               // 6 x M1E el = [20,23)

    const int nElem = NTOK * D_;                // 1,048,576

    detect_kernel<<<1, 256, 0, stream>>>(enc, flag);
    prep_w_kernel<<<3072, 256, 0, stream>>>(
        sa_Wq, sa_Wk, sa_Wv, sa_Wo, ca_Wq, ca_Wk, ca_Wv, ca_Wo,
        ff_W1, ff_W2, Wf, flag);
    pe_build_kernel<<<(LD_ * D_) / 256, 256, 0, stream>>>(pe);
    embed_kernel<<<nElem / 256, 256, 0, stream>>>(dec, W_tgt, b_tgt, x, xhi, xlo, pe, flag);
    enc_split_kernel<<<nElem / 256, 256, 0, stream>>>(enc, enchi, enclo, flag);
    // hoisted cross-attn K/V for all 6 layers (depends only on enc + weights)
    gemmkv_kernel<<<dim3(4, 128, 12), 256, 0, stream>>>(
        enchi, enclo, Wf, ca_bk, ca_bv, kvK, kvV, flag);

    dim3 gProj3(D_ / 64, NTOK / 32, 3);         // (4,128,3)
    dim3 gProj1(D_ / 64, NTOK / 32, 1);         // (4,128,1)
    dim3 gAttn(LD_ / 64, H_, B_);               // (16,8,4)

    for (int i = 0; i < NL_; ++i) {
        const size_t LB   = (size_t)i * 1048576;   // layer base in Wf (elements)
        const size_t bOff = (size_t)i * D_;

        // --- self attention ---
        gemmf_kernel<<<gProj3, 256, 0, stream>>>(
            xhi, xlo, xhi, xlo, xhi, xlo,
            Wf, LB, 65536, sa_bq, sa_bk, sa_bv, bOff,
            qbuf, kbuf, vtbuf, NTOK, D_, D_, flag);
        fattn4_kernel<<<gAttn, 256, 0, stream>>>(qbuf, kbuf, vtbuf, ctxhi, ctxlo, dec_masks, 1);
        gemmln_kernel<<<NTOK / 16, 1024, 0, stream>>>(
            ctxhi, ctxlo, Wf, LB + 3 * 65536, sa_bo, x, xhi, xlo,
            sa_ln_g, sa_ln_b, bOff, D_, pe, 0, flag);

        // --- cross attention (K/V pre-hoisted; Q only on critical path) ---
        gemmf_kernel<<<gProj1, 256, 0, stream>>>(
            xhi, xlo, xhi, xlo, xhi, xlo,
            Wf, LB + 4 * 65536, 65536, ca_bq, ca_bq, ca_bq, bOff,
            qbuf, qbuf, qbuf, NTOK, D_, D_, flag);
        fattn4_kernel<<<gAttn, 256, 0, stream>>>(
            qbuf, kvK + (size_t)i * 2 * M1E, kvV + (size_t)i * M1E,
            ctxhi, ctxlo, enc_masks, 0);
        gemmln_kernel<<<NTOK / 16, 1024, 0, stream>>>(
            ctxhi, ctxlo, Wf, LB + 7 * 65536, ca_bo, x, xhi, xlo,
            ca_ln_g, ca_ln_b, bOff, D_, pe, 0, flag);

        // --- fused FFN (FF1 + relu + FF2 + residual + LN [+pe] [+out]) ---
        ffn_kernel<<<NTOK / 16, 1024, 0, stream>>>(
            xhi, xlo, Wf, LB + 524288, LB + 786432,
            ff_b1, ff_b2, (size_t)i * DFF_, bOff, x, xhi, xlo,
            ff_ln_g, ff_ln_b, pe, (i < NL_ - 1) ? 1 : 0,
            d_out, (i == NL_ - 1) ? 1 : 0, flag);
    }
}